// Round 3
// baseline (769.448 us; speedup 1.0000x reference)
//
#include <hip/hip_runtime.h>

#define D 64

// ================= CSR build =================

__global__ void hist_kernel(const int* __restrict__ dst, int* __restrict__ deg, int E) {
    int i = blockIdx.x * blockDim.x + threadIdx.x;
    int n = gridDim.x * blockDim.x;
    for (int e = i; e < E; e += n) atomicAdd(&deg[dst[e]], 1);
}

__global__ void invdeg_kernel(const int* __restrict__ deg, float* __restrict__ inv, int N) {
    int i = blockIdx.x * blockDim.x + threadIdx.x;
    if (i < N) inv[i] = 1.0f / fmaxf((float)deg[i], 1.0f);
}

__global__ void blocksum_kernel(const int* __restrict__ deg, int* __restrict__ blockSums, int N) {
    __shared__ int s[256];
    int t = threadIdx.x;
    int i = blockIdx.x * 256 + t;
    s[t] = (i < N) ? deg[i] : 0;
    __syncthreads();
    for (int d = 128; d > 0; d >>= 1) {
        if (t < d) s[t] += s[t + d];
        __syncthreads();
    }
    if (t == 0) blockSums[blockIdx.x] = s[0];
}

// single block, 512 threads; nb <= 512
__global__ void scanpartials_kernel(const int* __restrict__ blockSums, int* __restrict__ blockOffs, int nb) {
    __shared__ int s[512];
    int t = threadIdx.x;
    int v = (t < nb) ? blockSums[t] : 0;
    s[t] = v;
    __syncthreads();
    for (int d = 1; d < 512; d <<= 1) {
        int add = (t >= d) ? s[t - d] : 0;
        __syncthreads();
        s[t] += add;
        __syncthreads();
    }
    if (t < nb) blockOffs[t] = s[t] - v;  // exclusive
}

__global__ void scanblock_kernel(const int* __restrict__ deg, const int* __restrict__ blockOffs,
                                 int* __restrict__ rowStart, int N) {
    __shared__ int s[256];
    int t = threadIdx.x;
    int i = blockIdx.x * 256 + t;
    int v = (i < N) ? deg[i] : 0;
    s[t] = v;
    __syncthreads();
    for (int d = 1; d < 256; d <<= 1) {
        int add = (t >= d) ? s[t - d] : 0;
        __syncthreads();
        s[t] += add;
        __syncthreads();
    }
    if (i < N) rowStart[i] = blockOffs[blockIdx.x] + s[t] - v;
    if (i == N - 1) rowStart[N] = blockOffs[blockIdx.x] + s[t];
}

__global__ void scatter_kernel(const int* __restrict__ src, const int* __restrict__ dst,
                               const int* __restrict__ rowStart, int* __restrict__ cursor,
                               int* __restrict__ csr, int E) {
    int i = blockIdx.x * blockDim.x + threadIdx.x;
    int n = gridDim.x * blockDim.x;
    for (int e = i; e < E; e += n) {
        int d = dst[e];
        int pos = rowStart[d] + atomicAdd(&cursor[d], 1);
        csr[pos] = src[e];
    }
}

// ================= aggregate: agg[n][:] = inv_deg[n] * sum_{j in N(n)} h[j][:] =================
// 4 groups of 16 lanes; group g takes every 4th edge -> 4 independent 256B gathers
// in flight per iteration (vs 1), csr reads for the 4 groups coalesce into 16B.
__global__ __launch_bounds__(256) void aggregate_csr4(
    const float* __restrict__ h, const int* __restrict__ rowStart,
    const int* __restrict__ csr, const float* __restrict__ inv_deg,
    float* __restrict__ agg, int N) {
    int wid  = (blockIdx.x * blockDim.x + threadIdx.x) >> 6;
    int lane = threadIdx.x & 63;
    int nw   = (gridDim.x * blockDim.x) >> 6;
    int g = lane >> 4;   // 0..3: edge subset
    int q = lane & 15;   // feature quad
    for (int node = wid; node < N; node += nw) {
        int beg = rowStart[node], end = rowStart[node + 1];
        float4 acc = {0.f, 0.f, 0.f, 0.f};
        for (int p = beg + g; p < end; p += 4) {
            int s = csr[p];
            float4 v = ((const float4*)(h + (size_t)s * D))[q];
            acc.x += v.x; acc.y += v.y; acc.z += v.z; acc.w += v.w;
        }
        // combine the 4 groups (butterfly over lane bits 4,5)
        acc.x += __shfl_xor(acc.x, 16); acc.y += __shfl_xor(acc.y, 16);
        acc.z += __shfl_xor(acc.z, 16); acc.w += __shfl_xor(acc.w, 16);
        acc.x += __shfl_xor(acc.x, 32); acc.y += __shfl_xor(acc.y, 32);
        acc.z += __shfl_xor(acc.z, 32); acc.w += __shfl_xor(acc.w, 32);
        if (g == 0) {
            float inv = inv_deg[node];
            float4 r;
            r.x = acc.x * inv; r.y = acc.y * inv; r.z = acc.z * inv; r.w = acc.w * inv;
            ((float4*)(agg + (size_t)node * D))[q] = r;
        }
    }
}

// ================= transform: out = [relu](agg @ Wl^T + bl + h @ Wr^T) [+ classifier] =================
// Weights in 128 VGPRs (lane o holds rows o of Wl and Wr). Row values arrive as
// same-address broadcast global_load_dwordx4 (L1/L2-hit) -- no LDS at all.
// Safe for out == agg (one wave owns a row; all reads precede the store).
template <bool RELU, bool CLS>
__global__ __launch_bounds__(256) void transform_bcast(
    const float* __restrict__ agg, const float* __restrict__ h,
    const float* __restrict__ Wl, const float* __restrict__ bl,
    const float* __restrict__ Wr,
    const float* __restrict__ Wout, const float* __restrict__ bout,
    float* __restrict__ out, int N) {
    int t = threadIdx.x;
    int lane = t & 63;
    int w = t >> 6;

    float4 wl[16], wr[16];
    const float4* Wl4 = (const float4*)(Wl + lane * D);
    const float4* Wr4 = (const float4*)(Wr + lane * D);
#pragma unroll
    for (int c = 0; c < 16; ++c) { wl[c] = Wl4[c]; wr[c] = Wr4[c]; }
    float b = bl[lane];
    float w0 = 0.f, w1 = 0.f, b0 = 0.f, b1 = 0.f;
    if (CLS) { w0 = Wout[lane]; w1 = Wout[D + lane]; b0 = bout[0]; b1 = bout[1]; }

    int stride = gridDim.x * 4;
    for (int r = blockIdx.x * 4 + w; r < N; r += stride) {
        const float4* ar = (const float4*)(agg + (size_t)r * D);  // wave-uniform addr
        const float4* hr = (const float4*)(h + (size_t)r * D);
        float accL = 0.0f, accR = 0.0f;
#pragma unroll
        for (int c = 0; c < 16; ++c) {
            float4 a4 = ar[c];   // broadcast load: all lanes same 16B
            float4 h4 = hr[c];
            accL += a4.x * wl[c].x + a4.y * wl[c].y + a4.z * wl[c].z + a4.w * wl[c].w;
            accR += h4.x * wr[c].x + h4.y * wr[c].y + h4.z * wr[c].z + h4.w * wr[c].w;
        }
        float v = accL + b + accR;
        if (RELU) v = fmaxf(v, 0.0f);
        if (CLS) {
            float a0 = v * w0;
            float a1 = v * w1;
#pragma unroll
            for (int off = 32; off > 0; off >>= 1) {
                a0 += __shfl_down(a0, off);
                a1 += __shfl_down(a1, off);
            }
            if (lane == 0) {
                out[(size_t)r * 2 + 0] = a0 + b0;
                out[(size_t)r * 2 + 1] = a1 + b1;
            }
        } else {
            out[(size_t)r * D + lane] = v;
        }
    }
}

extern "C" void kernel_launch(void* const* d_in, const int* in_sizes, int n_in,
                              void* d_out, int out_size, void* d_ws, size_t ws_size,
                              hipStream_t stream) {
    const float* x    = (const float*)d_in[0];
    const int*   ei   = (const int*)d_in[1];
    const float* Wl   = (const float*)d_in[2];
    const float* bl   = (const float*)d_in[3];
    const float* Wr   = (const float*)d_in[4];
    const float* Wout = (const float*)d_in[5];
    const float* bout = (const float*)d_in[6];
    float*       out  = (float*)d_out;

    const int N = in_sizes[0] / D;
    const int E = in_sizes[1] / 2;
    const int* src = ei;
    const int* dst = ei + E;
    const int nb = (N + 255) / 256;

    char* ws = (char*)d_ws;
    size_t off = 0;
    auto alloc = [&](size_t bytes) {
        char* p = ws + off;
        off = (off + bytes + 255) & ~(size_t)255;
        return p;
    };
    int*   deg_i     = (int*)alloc((size_t)N * 4);
    float* inv_deg   = (float*)alloc((size_t)N * 4);
    int*   rowStart  = (int*)alloc((size_t)(N + 1) * 4);
    int*   cursor    = (int*)alloc((size_t)N * 4);
    int*   blockSums = (int*)alloc((size_t)nb * 4);
    int*   blockOffs = (int*)alloc((size_t)nb * 4);
    int*   csr       = (int*)alloc((size_t)E * 4);
    float* bufA      = (float*)alloc((size_t)N * D * 4);
    float* bufB      = (float*)alloc((size_t)N * D * 4);

    hipMemsetAsync(deg_i, 0, (size_t)N * 4, stream);
    hipMemsetAsync(cursor, 0, (size_t)N * 4, stream);

    // ---- CSR build (once, reused by all 3 layers) ----
    hist_kernel<<<1024, 256, 0, stream>>>(dst, deg_i, E);
    invdeg_kernel<<<nb, 256, 0, stream>>>(deg_i, inv_deg, N);
    blocksum_kernel<<<nb, 256, 0, stream>>>(deg_i, blockSums, N);
    scanpartials_kernel<<<1, 512, 0, stream>>>(blockSums, blockOffs, nb);
    scanblock_kernel<<<nb, 256, 0, stream>>>(deg_i, blockOffs, rowStart, N);
    scatter_kernel<<<2048, 256, 0, stream>>>(src, dst, rowStart, cursor, csr, E);

    // ---- 3 layers ----
    aggregate_csr4<<<2048, 256, 0, stream>>>(x, rowStart, csr, inv_deg, bufA, N);
    transform_bcast<true, false><<<1024, 256, 0, stream>>>(bufA, x, Wl, bl, Wr, nullptr, nullptr, bufA, N);

    aggregate_csr4<<<2048, 256, 0, stream>>>(bufA, rowStart, csr, inv_deg, bufB, N);
    transform_bcast<true, false><<<1024, 256, 0, stream>>>(bufB, bufA, Wl + D * D, bl + D, Wr + D * D, nullptr, nullptr, bufB, N);

    aggregate_csr4<<<2048, 256, 0, stream>>>(bufB, rowStart, csr, inv_deg, bufA, N);
    transform_bcast<false, true><<<1024, 256, 0, stream>>>(bufA, bufB, Wl + 2 * D * D, bl + 2 * D, Wr + 2 * D * D, Wout, bout, out, N);
}

// Round 4
// 622.286 us; speedup vs baseline: 1.2365x; 1.2365x over previous
//
#include <hip/hip_runtime.h>

#define D 64

// ================= CSR build =================

__global__ void hist_kernel(const int* __restrict__ dst, int* __restrict__ deg, int E) {
    int i = blockIdx.x * blockDim.x + threadIdx.x;
    int n = gridDim.x * blockDim.x;
    for (int e = i; e < E; e += n) atomicAdd(&deg[dst[e]], 1);
}

__global__ void blocksum_kernel(const int* __restrict__ deg, int* __restrict__ blockSums, int N) {
    __shared__ int s[256];
    int t = threadIdx.x;
    int i = blockIdx.x * 256 + t;
    s[t] = (i < N) ? deg[i] : 0;
    __syncthreads();
    for (int d = 128; d > 0; d >>= 1) {
        if (t < d) s[t] += s[t + d];
        __syncthreads();
    }
    if (t == 0) blockSums[blockIdx.x] = s[0];
}

// single block, 512 threads; nb <= 512
__global__ void scanpartials_kernel(const int* __restrict__ blockSums, int* __restrict__ blockOffs, int nb) {
    __shared__ int s[512];
    int t = threadIdx.x;
    int v = (t < nb) ? blockSums[t] : 0;
    s[t] = v;
    __syncthreads();
    for (int d = 1; d < 512; d <<= 1) {
        int add = (t >= d) ? s[t - d] : 0;
        __syncthreads();
        s[t] += add;
        __syncthreads();
    }
    if (t < nb) blockOffs[t] = s[t] - v;  // exclusive
}

__global__ void scanblock_kernel(const int* __restrict__ deg, const int* __restrict__ blockOffs,
                                 int* __restrict__ rowStart, int N) {
    __shared__ int s[256];
    int t = threadIdx.x;
    int i = blockIdx.x * 256 + t;
    int v = (i < N) ? deg[i] : 0;
    s[t] = v;
    __syncthreads();
    for (int d = 1; d < 256; d <<= 1) {
        int add = (t >= d) ? s[t - d] : 0;
        __syncthreads();
        s[t] += add;
        __syncthreads();
    }
    if (i < N) rowStart[i] = blockOffs[blockIdx.x] + s[t] - v;
    if (i == N - 1) rowStart[N] = blockOffs[blockIdx.x] + s[t];
}

__global__ void scatter_kernel(const int* __restrict__ src, const int* __restrict__ dst,
                               const int* __restrict__ rowStart, int* __restrict__ cursor,
                               int* __restrict__ csr, int E) {
    int i = blockIdx.x * blockDim.x + threadIdx.x;
    int n = gridDim.x * blockDim.x;
    for (int e = i; e < E; e += n) {
        int d = dst[e];
        int pos = rowStart[d] + atomicAdd(&cursor[d], 1);
        csr[pos] = src[e];
    }
}

// ================= fused layer =================
// out = [relu]( mean_{j in N(n)} h[j] @ Wl^T + bl + h[n] @ Wr^T )   [+ classifier]
//
// Per node, one wave:
//  - gather: 4 groups of 16 lanes, group g sums every 4th neighbor row (quad q
//    per lane) -> 4 independent 256B gathers in flight; butterfly over lane
//    bits 4,5 leaves the full quad-sum in every lane.
//  - stage: ONE masked ds_write_b128 (g==0: agg*inv, g==1: own h row quad)
//    puts both 256B rows in wave-private LDS.
//  - dual GEMV: weights in 128 VGPRs (lane o = rows o of Wl,Wr), rows read
//    back as 32 broadcast ds_read_b128 (LDS-latency, hidden at 8 waves/CU).
// No inter-wave comms, no __syncthreads, agg never touches global memory.
template <bool RELU, bool CLS>
__global__ __launch_bounds__(256) void layer_fused(
    const float* __restrict__ h, const int* __restrict__ rowStart,
    const int* __restrict__ csr,
    const float* __restrict__ Wl, const float* __restrict__ bl,
    const float* __restrict__ Wr,
    const float* __restrict__ Wout, const float* __restrict__ bout,
    float* __restrict__ out, int N) {
    int t = threadIdx.x;
    int lane = t & 63;
    int w = t >> 6;
    int g = lane >> 4;   // edge subset / stager role
    int q = lane & 15;   // feature quad

    float4 wl[16], wr[16];
    const float4* Wl4 = (const float4*)(Wl + lane * D);
    const float4* Wr4 = (const float4*)(Wr + lane * D);
#pragma unroll
    for (int c = 0; c < 16; ++c) { wl[c] = Wl4[c]; wr[c] = Wr4[c]; }
    float b = bl[lane];
    float w0 = 0.f, w1 = 0.f, b0 = 0.f, b1 = 0.f;
    if (CLS) { w0 = Wout[lane]; w1 = Wout[D + lane]; b0 = bout[0]; b1 = bout[1]; }

    __shared__ float rowbuf[4][2][D];  // [wave][agg|h][feature] — wave-private

    int stride = gridDim.x * 4;
    for (int node = blockIdx.x * 4 + w; node < N; node += stride) {
        int beg = rowStart[node], end = rowStart[node + 1];
        // own-row load issued early, overlaps the gather chain
        float4 hq = ((const float4*)(h + (size_t)node * D))[q];
        float4 acc = {0.f, 0.f, 0.f, 0.f};
        for (int p = beg + g; p < end; p += 4) {
            int s = csr[p];
            float4 v = ((const float4*)(h + (size_t)s * D))[q];
            acc.x += v.x; acc.y += v.y; acc.z += v.z; acc.w += v.w;
        }
        // combine 4 edge-groups: butterfly over lane bits 4,5
        acc.x += __shfl_xor(acc.x, 16); acc.y += __shfl_xor(acc.y, 16);
        acc.z += __shfl_xor(acc.z, 16); acc.w += __shfl_xor(acc.w, 16);
        acc.x += __shfl_xor(acc.x, 32); acc.y += __shfl_xor(acc.y, 32);
        acc.z += __shfl_xor(acc.z, 32); acc.w += __shfl_xor(acc.w, 32);

        float inv = 1.0f / fmaxf((float)(end - beg), 1.0f);
        float4 wdata;
        wdata.x = acc.x * inv; wdata.y = acc.y * inv;
        wdata.z = acc.z * inv; wdata.w = acc.w * inv;
        if (g == 1) wdata = hq;
        if (g < 2) *((float4*)&rowbuf[w][g][q * 4]) = wdata;  // one masked b128 write

        float accL = 0.0f, accR = 0.0f;
#pragma unroll
        for (int c = 0; c < 16; ++c) {
            float4 a4 = *((const float4*)&rowbuf[w][0][c * 4]);  // broadcast b128
            float4 h4 = *((const float4*)&rowbuf[w][1][c * 4]);
            accL += a4.x * wl[c].x + a4.y * wl[c].y + a4.z * wl[c].z + a4.w * wl[c].w;
            accR += h4.x * wr[c].x + h4.y * wr[c].y + h4.z * wr[c].z + h4.w * wr[c].w;
        }
        float v = accL + b + accR;
        if (RELU) v = fmaxf(v, 0.0f);
        if (CLS) {
            float a0 = v * w0;
            float a1 = v * w1;
#pragma unroll
            for (int off = 32; off > 0; off >>= 1) {
                a0 += __shfl_down(a0, off);
                a1 += __shfl_down(a1, off);
            }
            if (lane == 0) {
                out[(size_t)node * 2 + 0] = a0 + b0;
                out[(size_t)node * 2 + 1] = a1 + b1;
            }
        } else {
            out[(size_t)node * D + lane] = v;
        }
    }
}

extern "C" void kernel_launch(void* const* d_in, const int* in_sizes, int n_in,
                              void* d_out, int out_size, void* d_ws, size_t ws_size,
                              hipStream_t stream) {
    const float* x    = (const float*)d_in[0];
    const int*   ei   = (const int*)d_in[1];
    const float* Wl   = (const float*)d_in[2];
    const float* bl   = (const float*)d_in[3];
    const float* Wr   = (const float*)d_in[4];
    const float* Wout = (const float*)d_in[5];
    const float* bout = (const float*)d_in[6];
    float*       out  = (float*)d_out;

    const int N = in_sizes[0] / D;
    const int E = in_sizes[1] / 2;
    const int* src = ei;
    const int* dst = ei + E;
    const int nb = (N + 255) / 256;

    char* ws = (char*)d_ws;
    size_t off = 0;
    auto alloc = [&](size_t bytes) {
        char* p = ws + off;
        off = (off + bytes + 255) & ~(size_t)255;
        return p;
    };
    int*   deg_i     = (int*)alloc((size_t)N * 4);
    int*   rowStart  = (int*)alloc((size_t)(N + 1) * 4);
    int*   cursor    = (int*)alloc((size_t)N * 4);
    int*   blockSums = (int*)alloc((size_t)nb * 4);
    int*   blockOffs = (int*)alloc((size_t)nb * 4);
    int*   csr       = (int*)alloc((size_t)E * 4);
    float* bufA      = (float*)alloc((size_t)N * D * 4);
    float* bufB      = (float*)alloc((size_t)N * D * 4);

    hipMemsetAsync(deg_i, 0, (size_t)N * 4, stream);
    hipMemsetAsync(cursor, 0, (size_t)N * 4, stream);

    // ---- CSR build (once, reused by all 3 layers) ----
    hist_kernel<<<1024, 256, 0, stream>>>(dst, deg_i, E);
    blocksum_kernel<<<nb, 256, 0, stream>>>(deg_i, blockSums, N);
    scanpartials_kernel<<<1, 512, 0, stream>>>(blockSums, blockOffs, nb);
    scanblock_kernel<<<nb, 256, 0, stream>>>(deg_i, blockOffs, rowStart, N);
    scatter_kernel<<<2048, 256, 0, stream>>>(src, dst, rowStart, cursor, csr, E);

    // ---- 3 fused layers ----
    layer_fused<true, false><<<2048, 256, 0, stream>>>(
        x, rowStart, csr, Wl, bl, Wr, nullptr, nullptr, bufA, N);
    layer_fused<true, false><<<2048, 256, 0, stream>>>(
        bufA, rowStart, csr, Wl + D * D, bl + D, Wr + D * D, nullptr, nullptr, bufB, N);
    layer_fused<false, true><<<2048, 256, 0, stream>>>(
        bufB, rowStart, csr, Wl + 2 * D * D, bl + 2 * D, Wr + 2 * D * D, Wout, bout, out, N);
}

// Round 5
// 450.999 us; speedup vs baseline: 1.7061x; 1.3798x over previous
//
#include <hip/hip_runtime.h>

#define D 64

// ================= CSR build =================

__global__ void hist_kernel(const int* __restrict__ dst, int* __restrict__ deg, int E) {
    int i = blockIdx.x * blockDim.x + threadIdx.x;
    int n = gridDim.x * blockDim.x;
    for (int e = i; e < E; e += n) atomicAdd(&deg[dst[e]], 1);
}

__global__ void blocksum_kernel(const int* __restrict__ deg, int* __restrict__ blockSums, int N) {
    __shared__ int s[256];
    int t = threadIdx.x;
    int i = blockIdx.x * 256 + t;
    s[t] = (i < N) ? deg[i] : 0;
    __syncthreads();
    for (int d = 128; d > 0; d >>= 1) {
        if (t < d) s[t] += s[t + d];
        __syncthreads();
    }
    if (t == 0) blockSums[blockIdx.x] = s[0];
}

// single block, 512 threads; nb <= 512
__global__ void scanpartials_kernel(const int* __restrict__ blockSums, int* __restrict__ blockOffs, int nb) {
    __shared__ int s[512];
    int t = threadIdx.x;
    int v = (t < nb) ? blockSums[t] : 0;
    s[t] = v;
    __syncthreads();
    for (int d = 1; d < 512; d <<= 1) {
        int add = (t >= d) ? s[t - d] : 0;
        __syncthreads();
        s[t] += add;
        __syncthreads();
    }
    if (t < nb) blockOffs[t] = s[t] - v;  // exclusive
}

__global__ void scanblock_kernel(const int* __restrict__ deg, const int* __restrict__ blockOffs,
                                 int* __restrict__ rowStart, int N) {
    __shared__ int s[256];
    int t = threadIdx.x;
    int i = blockIdx.x * 256 + t;
    int v = (i < N) ? deg[i] : 0;
    s[t] = v;
    __syncthreads();
    for (int d = 1; d < 256; d <<= 1) {
        int add = (t >= d) ? s[t - d] : 0;
        __syncthreads();
        s[t] += add;
        __syncthreads();
    }
    if (i < N) rowStart[i] = blockOffs[blockIdx.x] + s[t] - v;
    if (i == N - 1) rowStart[N] = blockOffs[blockIdx.x] + s[t];
}

__global__ void scatter_kernel(const int* __restrict__ src, const int* __restrict__ dst,
                               const int* __restrict__ rowStart, int* __restrict__ cursor,
                               int* __restrict__ csr, int E) {
    int i = blockIdx.x * blockDim.x + threadIdx.x;
    int n = gridDim.x * blockDim.x;
    for (int e = i; e < E; e += n) {
        int d = dst[e];
        int pos = rowStart[d] + atomicAdd(&cursor[d], 1);
        csr[pos] = src[e];
    }
}

// ================= aggregate: agg[n][:] = inv_deg[n] * sum_{j in N(n)} h[j][:] =================
// 4 groups of 16 lanes; group g takes every 4th edge -> 4 independent 256B gathers
// in flight per iteration; csr reads for the 4 groups coalesce. inv_deg from rowStart.
__global__ __launch_bounds__(256) void aggregate_csr4(
    const float* __restrict__ h, const int* __restrict__ rowStart,
    const int* __restrict__ csr, float* __restrict__ agg, int N) {
    int wid  = (blockIdx.x * blockDim.x + threadIdx.x) >> 6;
    int lane = threadIdx.x & 63;
    int nw   = (gridDim.x * blockDim.x) >> 6;
    int g = lane >> 4;   // 0..3: edge subset
    int q = lane & 15;   // feature quad
    for (int node = wid; node < N; node += nw) {
        int beg = rowStart[node], end = rowStart[node + 1];
        float4 acc = {0.f, 0.f, 0.f, 0.f};
        for (int p = beg + g; p < end; p += 4) {
            int s = csr[p];
            float4 v = ((const float4*)(h + (size_t)s * D))[q];
            acc.x += v.x; acc.y += v.y; acc.z += v.z; acc.w += v.w;
        }
        // combine the 4 groups (butterfly over lane bits 4,5)
        acc.x += __shfl_xor(acc.x, 16); acc.y += __shfl_xor(acc.y, 16);
        acc.z += __shfl_xor(acc.z, 16); acc.w += __shfl_xor(acc.w, 16);
        acc.x += __shfl_xor(acc.x, 32); acc.y += __shfl_xor(acc.y, 32);
        acc.z += __shfl_xor(acc.z, 32); acc.w += __shfl_xor(acc.w, 32);
        if (g == 0) {
            float inv = 1.0f / fmaxf((float)(end - beg), 1.0f);
            float4 r;
            r.x = acc.x * inv; r.y = acc.y * inv; r.z = acc.z * inv; r.w = acc.w * inv;
            ((float4*)(agg + (size_t)node * D))[q] = r;
        }
    }
}

// broadcast lane k's float to the whole wave via v_readlane (SGPR result;
// feeds v_fma as its one allowed scalar operand — no LDS traffic at all)
__device__ __forceinline__ float bc(float x, int k) {
    return __int_as_float(__builtin_amdgcn_readlane(__float_as_int(x), k));
}

// ================= transform: out = [relu](agg @ Wl^T + bl + h @ Wr^T) [+ classifier] =================
// One wave per row. Lane o holds Wl/Wr row o in 128 VGPRs (constant-indexed ->
// registers). Row data: ONE coalesced dword per lane, elements broadcast via
// readlane. 4 independent FMA chains for ILP. Safe for out == agg.
template <bool RELU, bool CLS>
__global__ __launch_bounds__(256, 2) void transform_rl(
    const float* __restrict__ agg, const float* __restrict__ h,
    const float* __restrict__ Wl, const float* __restrict__ bl,
    const float* __restrict__ Wr,
    const float* __restrict__ Wout, const float* __restrict__ bout,
    float* __restrict__ out, int N) {
    int t = threadIdx.x;
    int lane = t & 63;
    int w = t >> 6;

    float wl[D], wr[D];
    const float4* Wl4 = (const float4*)(Wl + lane * D);
    const float4* Wr4 = (const float4*)(Wr + lane * D);
#pragma unroll
    for (int c = 0; c < 16; ++c) {
        float4 a = Wl4[c], b4 = Wr4[c];
        wl[c * 4 + 0] = a.x; wl[c * 4 + 1] = a.y; wl[c * 4 + 2] = a.z; wl[c * 4 + 3] = a.w;
        wr[c * 4 + 0] = b4.x; wr[c * 4 + 1] = b4.y; wr[c * 4 + 2] = b4.z; wr[c * 4 + 3] = b4.w;
    }
    float b = bl[lane];
    float w0 = 0.f, w1 = 0.f, b0 = 0.f, b1 = 0.f;
    if (CLS) { w0 = Wout[lane]; w1 = Wout[D + lane]; b0 = bout[0]; b1 = bout[1]; }

    int stride = gridDim.x * 4;
    for (int r = blockIdx.x * 4 + w; r < N; r += stride) {
        float rA = agg[(size_t)r * D + lane];  // one coalesced dword each
        float rH = h[(size_t)r * D + lane];
        float acc0 = 0.f, acc1 = 0.f, acc2 = 0.f, acc3 = 0.f;
#pragma unroll
        for (int kk = 0; kk < 16; ++kk) {
            acc0 = fmaf(bc(rA, kk),      wl[kk],      fmaf(bc(rH, kk),      wr[kk],      acc0));
            acc1 = fmaf(bc(rA, 16 + kk), wl[16 + kk], fmaf(bc(rH, 16 + kk), wr[16 + kk], acc1));
            acc2 = fmaf(bc(rA, 32 + kk), wl[32 + kk], fmaf(bc(rH, 32 + kk), wr[32 + kk], acc2));
            acc3 = fmaf(bc(rA, 48 + kk), wl[48 + kk], fmaf(bc(rH, 48 + kk), wr[48 + kk], acc3));
        }
        float v = ((acc0 + acc1) + (acc2 + acc3)) + b;
        if (RELU) v = fmaxf(v, 0.0f);
        if (CLS) {
            float a0 = v * w0;
            float a1 = v * w1;
#pragma unroll
            for (int off = 32; off > 0; off >>= 1) {
                a0 += __shfl_down(a0, off);
                a1 += __shfl_down(a1, off);
            }
            if (lane == 0) {
                out[(size_t)r * 2 + 0] = a0 + b0;
                out[(size_t)r * 2 + 1] = a1 + b1;
            }
        } else {
            out[(size_t)r * D + lane] = v;
        }
    }
}

extern "C" void kernel_launch(void* const* d_in, const int* in_sizes, int n_in,
                              void* d_out, int out_size, void* d_ws, size_t ws_size,
                              hipStream_t stream) {
    const float* x    = (const float*)d_in[0];
    const int*   ei   = (const int*)d_in[1];
    const float* Wl   = (const float*)d_in[2];
    const float* bl   = (const float*)d_in[3];
    const float* Wr   = (const float*)d_in[4];
    const float* Wout = (const float*)d_in[5];
    const float* bout = (const float*)d_in[6];
    float*       out  = (float*)d_out;

    const int N = in_sizes[0] / D;
    const int E = in_sizes[1] / 2;
    const int* src = ei;
    const int* dst = ei + E;
    const int nb = (N + 255) / 256;

    char* ws = (char*)d_ws;
    size_t off = 0;
    auto alloc = [&](size_t bytes) {
        char* p = ws + off;
        off = (off + bytes + 255) & ~(size_t)255;
        return p;
    };
    int*   deg_i     = (int*)alloc((size_t)N * 4);
    int*   rowStart  = (int*)alloc((size_t)(N + 1) * 4);
    int*   cursor    = (int*)alloc((size_t)N * 4);
    int*   blockSums = (int*)alloc((size_t)nb * 4);
    int*   blockOffs = (int*)alloc((size_t)nb * 4);
    int*   csr       = (int*)alloc((size_t)E * 4);
    float* bufA      = (float*)alloc((size_t)N * D * 4);
    float* bufB      = (float*)alloc((size_t)N * D * 4);

    hipMemsetAsync(deg_i, 0, (size_t)N * 4, stream);
    hipMemsetAsync(cursor, 0, (size_t)N * 4, stream);

    // ---- CSR build (once, reused by all 3 layers) ----
    hist_kernel<<<1024, 256, 0, stream>>>(dst, deg_i, E);
    blocksum_kernel<<<nb, 256, 0, stream>>>(deg_i, blockSums, N);
    scanpartials_kernel<<<1, 512, 0, stream>>>(blockSums, blockOffs, nb);
    scanblock_kernel<<<nb, 256, 0, stream>>>(deg_i, blockOffs, rowStart, N);
    scatter_kernel<<<2048, 256, 0, stream>>>(src, dst, rowStart, cursor, csr, E);

    // ---- 3 layers: agg into T, transform (T,H) -> T  (2-buffer ping-pong) ----
    aggregate_csr4<<<2048, 256, 0, stream>>>(x, rowStart, csr, bufA, N);
    transform_rl<true, false><<<2048, 256, 0, stream>>>(
        bufA, x, Wl, bl, Wr, nullptr, nullptr, bufA, N);

    aggregate_csr4<<<2048, 256, 0, stream>>>(bufA, rowStart, csr, bufB, N);
    transform_rl<true, false><<<2048, 256, 0, stream>>>(
        bufB, bufA, Wl + D * D, bl + D, Wr + D * D, nullptr, nullptr, bufB, N);

    aggregate_csr4<<<2048, 256, 0, stream>>>(bufB, rowStart, csr, bufA, N);
    transform_rl<false, true><<<2048, 256, 0, stream>>>(
        bufA, bufB, Wl + 2 * D * D, bl + 2 * D, Wr + 2 * D * D, Wout, bout, out, N);
}

// Round 6
// 295.866 us; speedup vs baseline: 2.6007x; 1.5243x over previous
//
#include <hip/hip_runtime.h>

#define D 64

typedef __attribute__((ext_vector_type(8))) short bf16x8;
typedef __attribute__((ext_vector_type(4))) float f32x4;

__device__ __forceinline__ unsigned short f2bf(float x) {
    union { float f; unsigned u; } v; v.f = x;
    unsigned r = v.u + 0x7fff + ((v.u >> 16) & 1);  // RNE
    return (unsigned short)(r >> 16);
}
__device__ __forceinline__ float bf2f_lo(unsigned u) { return __uint_as_float(u << 16); }
__device__ __forceinline__ float bf2f_hi(unsigned u) { return __uint_as_float(u & 0xffff0000u); }

// ================= CSR build =================

__global__ void hist_kernel(const int* __restrict__ dst, int* __restrict__ deg, int E) {
    int i = blockIdx.x * blockDim.x + threadIdx.x;
    int n = gridDim.x * blockDim.x;
    for (int e = i; e < E; e += n) atomicAdd(&deg[dst[e]], 1);
}

__global__ void blocksum_kernel(const int* __restrict__ deg, int* __restrict__ blockSums, int N) {
    __shared__ int s[256];
    int t = threadIdx.x;
    int i = blockIdx.x * 256 + t;
    s[t] = (i < N) ? deg[i] : 0;
    __syncthreads();
    for (int d = 128; d > 0; d >>= 1) {
        if (t < d) s[t] += s[t + d];
        __syncthreads();
    }
    if (t == 0) blockSums[blockIdx.x] = s[0];
}

__global__ void scanpartials_kernel(const int* __restrict__ blockSums, int* __restrict__ blockOffs, int nb) {
    __shared__ int s[512];
    int t = threadIdx.x;
    int v = (t < nb) ? blockSums[t] : 0;
    s[t] = v;
    __syncthreads();
    for (int d = 1; d < 512; d <<= 1) {
        int add = (t >= d) ? s[t - d] : 0;
        __syncthreads();
        s[t] += add;
        __syncthreads();
    }
    if (t < nb) blockOffs[t] = s[t] - v;  // exclusive
}

__global__ void scanblock_kernel(const int* __restrict__ deg, const int* __restrict__ blockOffs,
                                 int* __restrict__ rowStart, int N) {
    __shared__ int s[256];
    int t = threadIdx.x;
    int i = blockIdx.x * 256 + t;
    int v = (i < N) ? deg[i] : 0;
    s[t] = v;
    __syncthreads();
    for (int d = 1; d < 256; d <<= 1) {
        int add = (t >= d) ? s[t - d] : 0;
        __syncthreads();
        s[t] += add;
        __syncthreads();
    }
    if (i < N) rowStart[i] = blockOffs[blockIdx.x] + s[t] - v;
    if (i == N - 1) rowStart[N] = blockOffs[blockIdx.x] + s[t];
}

__global__ void scatter_kernel(const int* __restrict__ src, const int* __restrict__ dst,
                               const int* __restrict__ rowStart, int* __restrict__ cursor,
                               int* __restrict__ csr, int E) {
    int i = blockIdx.x * blockDim.x + threadIdx.x;
    int n = gridDim.x * blockDim.x;
    for (int e = i; e < E; e += n) {
        int d = dst[e];
        int pos = rowStart[d] + atomicAdd(&cursor[d], 1);
        csr[pos] = src[e];
    }
}

// ================= fp32 -> bf16 convert (x once) =================
__global__ void f2b_kernel(const float* __restrict__ in, unsigned short* __restrict__ out, int n4) {
    int i = blockIdx.x * blockDim.x + threadIdx.x;
    int stride = gridDim.x * blockDim.x;
    for (; i < n4; i += stride) {
        float4 v = ((const float4*)in)[i];
        ushort4 o;
        o.x = f2bf(v.x); o.y = f2bf(v.y); o.z = f2bf(v.z); o.w = f2bf(v.w);
        ((ushort4*)out)[i] = o;
    }
}

// ================= weight prep: pack Wcat = [Wl^T ; Wr^T] into per-lane MFMA A-fragments =================
// frag f = ot*4+ks; lane l, elem b  <-  A[o = ot*16+(l&15)][k = ks*32+(l>>4)*8+b]
// A[o][k] = (k<64 ? Wl[o][k] : Wr[o][k-64])   (out = agg@Wl^T + h@Wr^T)
// layout: wbuf[layer][f][lane][8]
__global__ void wprep_kernel(const float* __restrict__ Wl, const float* __restrict__ Wr,
                             unsigned short* __restrict__ wbuf) {
    int layer = blockIdx.x >> 4;
    int f = blockIdx.x & 15;
    int ot = f >> 2, ks = f & 3;
    int l = threadIdx.x;  // 64
    const float* W = (ks < 2 ? Wl : Wr) + (size_t)layer * D * D;
    const float* srcp = W + (size_t)(ot * 16 + (l & 15)) * D + (ks & 1) * 32 + (l >> 4) * 8;
    float4 w0 = *(const float4*)srcp;
    float4 w1 = *(const float4*)(srcp + 4);
    unsigned short* dstp = wbuf + (((size_t)layer * 16 + f) * 64 + l) * 8;
    dstp[0] = f2bf(w0.x); dstp[1] = f2bf(w0.y); dstp[2] = f2bf(w0.z); dstp[3] = f2bf(w0.w);
    dstp[4] = f2bf(w1.x); dstp[5] = f2bf(w1.y); dstp[6] = f2bf(w1.z); dstp[7] = f2bf(w1.w);
}

// ================= aggregate (bf16 in / bf16 out, fp32 accumulate) =================
// 4 groups of 16 lanes; group g takes every 4th edge -> 4 gathers in flight.
// Row is 128B bf16; lane q holds 8B (4 bf16). inv_deg from rowStart.
__global__ __launch_bounds__(256) void aggregate_bf16(
    const unsigned short* __restrict__ h, const int* __restrict__ rowStart,
    const int* __restrict__ csr, unsigned short* __restrict__ agg, int N) {
    int wid  = (blockIdx.x * blockDim.x + threadIdx.x) >> 6;
    int lane = threadIdx.x & 63;
    int nw   = (gridDim.x * blockDim.x) >> 6;
    int g = lane >> 4;   // edge subset
    int q = lane & 15;   // 8B chunk
    for (int node = wid; node < N; node += nw) {
        int beg = rowStart[node], end = rowStart[node + 1];
        float a0 = 0.f, a1 = 0.f, a2 = 0.f, a3 = 0.f;
        for (int p = beg + g; p < end; p += 4) {
            int s = csr[p];
            uint2 v = *(const uint2*)(h + (size_t)s * D + q * 4);
            a0 += bf2f_lo(v.x); a1 += bf2f_hi(v.x);
            a2 += bf2f_lo(v.y); a3 += bf2f_hi(v.y);
        }
        a0 += __shfl_xor(a0, 16); a1 += __shfl_xor(a1, 16);
        a2 += __shfl_xor(a2, 16); a3 += __shfl_xor(a3, 16);
        a0 += __shfl_xor(a0, 32); a1 += __shfl_xor(a1, 32);
        a2 += __shfl_xor(a2, 32); a3 += __shfl_xor(a3, 32);
        if (g == 0) {
            float inv = 1.0f / fmaxf((float)(end - beg), 1.0f);
            uint2 o;
            o.x = (unsigned)f2bf(a0 * inv) | ((unsigned)f2bf(a1 * inv) << 16);
            o.y = (unsigned)f2bf(a2 * inv) | ((unsigned)f2bf(a3 * inv) << 16);
            *(uint2*)(agg + (size_t)node * D + q * 4) = o;
        }
    }
}

// ================= transform via MFMA =================
// out[N,64] = relu?( [agg|h][N,128] @ Wcat[128,64] + bl )
// A-operand = weights (pre-packed frags), B-operand = data rows.
// Wave computes 16 rows x 64 cols: 4 otiles x 4 ksteps = 16 MFMA.
// B frag: lane l holds rows[r0+(l&15)][ks*32+(l>>4)*8 + 0..7]  (one 16B load)
// D: col(lane&15)=row index, row((lane>>4)*4+v)=feature -> 8B store of 4 bf16.
template <bool RELU>
__global__ __launch_bounds__(256) void transform_mfma(
    const unsigned short* __restrict__ agg, const unsigned short* __restrict__ h,
    const unsigned short* __restrict__ wbuf, const float* __restrict__ bl,
    unsigned short* __restrict__ out, int N) {
    int t = threadIdx.x;
    int lane = t & 63;
    int w = t >> 6;
    int rq = lane & 15;
    int kg = lane >> 4;

    bf16x8 wf[16];
#pragma unroll
    for (int f = 0; f < 16; ++f)
        wf[f] = *(const bf16x8*)(wbuf + ((size_t)f * 64 + lane) * 8);
    float4 bias[4];
#pragma unroll
    for (int ot = 0; ot < 4; ++ot)
        bias[ot] = *(const float4*)(bl + ot * 16 + kg * 4);

    int tiles = (N + 15) >> 4;
    for (int tile = blockIdx.x * 4 + w; tile < tiles; tile += gridDim.x * 4) {
        int r = tile * 16 + rq;
        int rc = min(r, N - 1);
        const unsigned short* ar = agg + (size_t)rc * D;
        const unsigned short* hr = h + (size_t)rc * D;
        bf16x8 d0 = *(const bf16x8*)(ar + kg * 8);
        bf16x8 d1 = *(const bf16x8*)(ar + 32 + kg * 8);
        bf16x8 d2 = *(const bf16x8*)(hr + kg * 8);
        bf16x8 d3 = *(const bf16x8*)(hr + 32 + kg * 8);

        f32x4 acc0 = {0.f, 0.f, 0.f, 0.f}, acc1 = acc0, acc2 = acc0, acc3 = acc0;
        acc0 = __builtin_amdgcn_mfma_f32_16x16x32_bf16(wf[0],  d0, acc0, 0, 0, 0);
        acc0 = __builtin_amdgcn_mfma_f32_16x16x32_bf16(wf[1],  d1, acc0, 0, 0, 0);
        acc0 = __builtin_amdgcn_mfma_f32_16x16x32_bf16(wf[2],  d2, acc0, 0, 0, 0);
        acc0 = __builtin_amdgcn_mfma_f32_16x16x32_bf16(wf[3],  d3, acc0, 0, 0, 0);
        acc1 = __builtin_amdgcn_mfma_f32_16x16x32_bf16(wf[4],  d0, acc1, 0, 0, 0);
        acc1 = __builtin_amdgcn_mfma_f32_16x16x32_bf16(wf[5],  d1, acc1, 0, 0, 0);
        acc1 = __builtin_amdgcn_mfma_f32_16x16x32_bf16(wf[6],  d2, acc1, 0, 0, 0);
        acc1 = __builtin_amdgcn_mfma_f32_16x16x32_bf16(wf[7],  d3, acc1, 0, 0, 0);
        acc2 = __builtin_amdgcn_mfma_f32_16x16x32_bf16(wf[8],  d0, acc2, 0, 0, 0);
        acc2 = __builtin_amdgcn_mfma_f32_16x16x32_bf16(wf[9],  d1, acc2, 0, 0, 0);
        acc2 = __builtin_amdgcn_mfma_f32_16x16x32_bf16(wf[10], d2, acc2, 0, 0, 0);
        acc2 = __builtin_amdgcn_mfma_f32_16x16x32_bf16(wf[11], d3, acc2, 0, 0, 0);
        acc3 = __builtin_amdgcn_mfma_f32_16x16x32_bf16(wf[12], d0, acc3, 0, 0, 0);
        acc3 = __builtin_amdgcn_mfma_f32_16x16x32_bf16(wf[13], d1, acc3, 0, 0, 0);
        acc3 = __builtin_amdgcn_mfma_f32_16x16x32_bf16(wf[14], d2, acc3, 0, 0, 0);
        acc3 = __builtin_amdgcn_mfma_f32_16x16x32_bf16(wf[15], d3, acc3, 0, 0, 0);

        if (r < N) {
            unsigned short* orow = out + (size_t)r * D + kg * 4;
            f32x4 av[4] = {acc0, acc1, acc2, acc3};
#pragma unroll
            for (int ot = 0; ot < 4; ++ot) {
                float x0 = av[ot][0] + bias[ot].x;
                float x1 = av[ot][1] + bias[ot].y;
                float x2 = av[ot][2] + bias[ot].z;
                float x3 = av[ot][3] + bias[ot].w;
                if (RELU) {
                    x0 = fmaxf(x0, 0.f); x1 = fmaxf(x1, 0.f);
                    x2 = fmaxf(x2, 0.f); x3 = fmaxf(x3, 0.f);
                }
                uint2 o;
                o.x = (unsigned)f2bf(x0) | ((unsigned)f2bf(x1) << 16);
                o.y = (unsigned)f2bf(x2) | ((unsigned)f2bf(x3) << 16);
                *(uint2*)(orow + ot * 16) = o;
            }
        }
    }
}

// ================= classifier: out[r][c] = h[r].Wout[c] + bout[c] (bf16 h) =================
__global__ void classify_bf16(const unsigned short* __restrict__ h,
                              const float* __restrict__ Wout,
                              const float* __restrict__ bout,
                              float* __restrict__ out, int N) {
    int wid  = (blockIdx.x * blockDim.x + threadIdx.x) >> 6;
    int lane = threadIdx.x & 63;
    int nw   = (gridDim.x * blockDim.x) >> 6;
    float w0 = Wout[lane];
    float w1 = Wout[D + lane];
    float b0 = bout[0], b1 = bout[1];
    for (int r = wid; r < N; r += nw) {
        float v = bf2f_lo((unsigned)h[(size_t)r * D + lane]);
        float a0 = v * w0;
        float a1 = v * w1;
#pragma unroll
        for (int off = 32; off > 0; off >>= 1) {
            a0 += __shfl_down(a0, off);
            a1 += __shfl_down(a1, off);
        }
        if (lane == 0) {
            out[(size_t)r * 2 + 0] = a0 + b0;
            out[(size_t)r * 2 + 1] = a1 + b1;
        }
    }
}

extern "C" void kernel_launch(void* const* d_in, const int* in_sizes, int n_in,
                              void* d_out, int out_size, void* d_ws, size_t ws_size,
                              hipStream_t stream) {
    const float* x    = (const float*)d_in[0];
    const int*   ei   = (const int*)d_in[1];
    const float* Wl   = (const float*)d_in[2];
    const float* bl   = (const float*)d_in[3];
    const float* Wr   = (const float*)d_in[4];
    const float* Wout = (const float*)d_in[5];
    const float* bout = (const float*)d_in[6];
    float*       out  = (float*)d_out;

    const int N = in_sizes[0] / D;
    const int E = in_sizes[1] / 2;
    const int* src = ei;
    const int* dst = ei + E;
    const int nb = (N + 255) / 256;

    char* ws = (char*)d_ws;
    size_t off = 0;
    auto alloc = [&](size_t bytes) {
        char* p = ws + off;
        off = (off + bytes + 255) & ~(size_t)255;
        return p;
    };
    int*            deg_i     = (int*)alloc((size_t)N * 4);
    int*            rowStart  = (int*)alloc((size_t)(N + 1) * 4);
    int*            cursor    = (int*)alloc((size_t)N * 4);
    int*            blockSums = (int*)alloc((size_t)nb * 4);
    int*            blockOffs = (int*)alloc((size_t)nb * 4);
    int*            csr       = (int*)alloc((size_t)E * 4);
    unsigned short* xb        = (unsigned short*)alloc((size_t)N * D * 2);
    unsigned short* hA        = (unsigned short*)alloc((size_t)N * D * 2);
    unsigned short* hB        = (unsigned short*)alloc((size_t)N * D * 2);
    unsigned short* aggB      = (unsigned short*)alloc((size_t)N * D * 2);
    unsigned short* wbuf      = (unsigned short*)alloc((size_t)3 * 16 * 64 * 8 * 2);

    hipMemsetAsync(deg_i, 0, (size_t)N * 4, stream);
    hipMemsetAsync(cursor, 0, (size_t)N * 4, stream);

    // ---- CSR build + conversions (independent of each other) ----
    hist_kernel<<<1024, 256, 0, stream>>>(dst, deg_i, E);
    blocksum_kernel<<<nb, 256, 0, stream>>>(deg_i, blockSums, N);
    scanpartials_kernel<<<1, 512, 0, stream>>>(blockSums, blockOffs, nb);
    scanblock_kernel<<<nb, 256, 0, stream>>>(deg_i, blockOffs, rowStart, N);
    scatter_kernel<<<2048, 256, 0, stream>>>(src, dst, rowStart, cursor, csr, E);
    f2b_kernel<<<2048, 256, 0, stream>>>(x, xb, N * D / 4);
    wprep_kernel<<<48, 64, 0, stream>>>(Wl, Wr, wbuf);

    const int WFRAG = 16 * 64 * 8;  // per-layer wbuf stride (ushorts)

    // ---- 3 layers ----
    aggregate_bf16<<<2048, 256, 0, stream>>>(xb, rowStart, csr, aggB, N);
    transform_mfma<true><<<1024, 256, 0, stream>>>(aggB, xb, wbuf, bl, hA, N);

    aggregate_bf16<<<2048, 256, 0, stream>>>(hA, rowStart, csr, aggB, N);
    transform_mfma<true><<<1024, 256, 0, stream>>>(aggB, hA, wbuf + WFRAG, bl + D, hB, N);

    aggregate_bf16<<<2048, 256, 0, stream>>>(hB, rowStart, csr, aggB, N);
    transform_mfma<false><<<1024, 256, 0, stream>>>(aggB, hB, wbuf + 2 * WFRAG, bl + 2 * D, hA, N);

    classify_bf16<<<1024, 256, 0, stream>>>(hA, Wout, bout, out, N);
}

// Round 8
// 204.907 us; speedup vs baseline: 3.7551x; 1.4439x over previous
//
#include <hip/hip_runtime.h>

#define D 64
#define NBMAX 512   // max buckets (N <= 131072)
#define BCAP 5120   // LDS csr staging capacity per bucket (mean 2560, 30+ sigma margin)

typedef __attribute__((ext_vector_type(8))) short bf16x8;
typedef __attribute__((ext_vector_type(4))) float f32x4;

__device__ __forceinline__ unsigned short f2bf(float x) {
    union { float f; unsigned u; } v; v.f = x;
    unsigned r = v.u + 0x7fff + ((v.u >> 16) & 1);  // RNE
    return (unsigned short)(r >> 16);
}
__device__ __forceinline__ float bf2f_lo(unsigned u) { return __uint_as_float(u << 16); }
__device__ __forceinline__ float bf2f_hi(unsigned u) { return __uint_as_float(u & 0xffff0000u); }

// ================= fp32 -> bf16 convert (x once) =================
__global__ void f2b_kernel(const float* __restrict__ in, unsigned short* __restrict__ out, int n4) {
    int i = blockIdx.x * blockDim.x + threadIdx.x;
    int stride = gridDim.x * blockDim.x;
    for (; i < n4; i += stride) {
        float4 v = ((const float4*)in)[i];
        ushort4 o;
        o.x = f2bf(v.x); o.y = f2bf(v.y); o.z = f2bf(v.z); o.w = f2bf(v.w);
        ((ushort4*)out)[i] = o;
    }
}

// ================= weight prep: pack Wcat = [Wl^T ; Wr^T] into per-lane MFMA A-fragments =================
__global__ void wprep_kernel(const float* __restrict__ Wl, const float* __restrict__ Wr,
                             unsigned short* __restrict__ wbuf) {
    int layer = blockIdx.x >> 4;
    int f = blockIdx.x & 15;
    int ot = f >> 2, ks = f & 3;
    int l = threadIdx.x;  // 64
    const float* W = (ks < 2 ? Wl : Wr) + (size_t)layer * D * D;
    const float* srcp = W + (size_t)(ot * 16 + (l & 15)) * D + (ks & 1) * 32 + (l >> 4) * 8;
    float4 w0 = *(const float4*)srcp;
    float4 w1 = *(const float4*)(srcp + 4);
    unsigned short* dstp = wbuf + (((size_t)layer * 16 + f) * 64 + l) * 8;
    dstp[0] = f2bf(w0.x); dstp[1] = f2bf(w0.y); dstp[2] = f2bf(w0.z); dstp[3] = f2bf(w0.w);
    dstp[4] = f2bf(w1.x); dstp[5] = f2bf(w1.y); dstp[6] = f2bf(w1.z); dstp[7] = f2bf(w1.w);
}

// ================= two-level CSR build =================
// bucket = dst >> 8 (256 nodes per bucket)

__global__ __launch_bounds__(256) void bin_count(const int* __restrict__ dst,
                                                 int* __restrict__ bucketCount, int E, int NB) {
    __shared__ int hst[NBMAX];
    int t = threadIdx.x;
    for (int i = t; i < NBMAX; i += 256) hst[i] = 0;
    __syncthreads();
    int per = (E + gridDim.x - 1) / gridDim.x;
    int beg = blockIdx.x * per;
    int end = min(E, beg + per);
    for (int e = beg + t; e < end; e += 256) atomicAdd(&hst[dst[e] >> 8], 1);
    __syncthreads();
    for (int i = t; i < NB; i += 256)
        if (hst[i]) atomicAdd(&bucketCount[i], hst[i]);
}

// 1 block, 512 threads: exclusive scan -> bucketStart[NB+1], init bucketCursor
__global__ void bucket_scan(const int* __restrict__ bucketCount, int* __restrict__ bucketStart,
                            int* __restrict__ bucketCursor, int NB) {
    __shared__ int s[512];
    int t = threadIdx.x;
    int v = (t < NB) ? bucketCount[t] : 0;
    s[t] = v;
    __syncthreads();
    for (int d = 1; d < 512; d <<= 1) {
        int add = (t >= d) ? s[t - d] : 0;
        __syncthreads();
        s[t] += add;
        __syncthreads();
    }
    if (t < NB) {
        bucketStart[t] = s[t] - v;
        bucketCursor[t] = s[t] - v;
        if (t == NB - 1) bucketStart[NB] = s[t];
    }
}

// bin edges into buckets; per-(block,bucket) ranges reserved via ONE atomic ->
// writes within a reservation are consecutive (write-combining works).
// binned entry (UNSIGNED): (dstLocal << 24) | src   (src < 2^24)
__global__ __launch_bounds__(256) void bin_scatter(const int* __restrict__ src,
                                                   const int* __restrict__ dst,
                                                   int* __restrict__ bucketCursor,
                                                   unsigned* __restrict__ binned, int E, int NB) {
    __shared__ int hst[NBMAX];
    int t = threadIdx.x;
    for (int i = t; i < NBMAX; i += 256) hst[i] = 0;
    __syncthreads();
    int per = (E + gridDim.x - 1) / gridDim.x;
    int beg = blockIdx.x * per;
    int end = min(E, beg + per);
    int ed[8];
#pragma unroll 8
    for (int k = 0; k < 8; ++k) {
        int e = beg + t + k * 256;
        if (e < end) {
            int d = dst[e];
            ed[k] = d;
            atomicAdd(&hst[d >> 8], 1);
        } else ed[k] = -1;
    }
    __syncthreads();
    for (int i = t; i < NB; i += 256) {
        int c = hst[i];
        if (c) hst[i] = atomicAdd(&bucketCursor[i], c);
    }
    __syncthreads();
#pragma unroll 8
    for (int k = 0; k < 8; ++k) {
        int e = beg + t + k * 256;
        if (e < end) {
            int d = ed[k];
            int pos = atomicAdd(&hst[d >> 8], 1);
            binned[pos] = (unsigned)src[e] | ((unsigned)(d & 255) << 24);
        }
    }
}

// one block per bucket: build exact per-node CSR in LDS, flush coalesced.
// also writes rowStart (global CSR offsets). deg = rowStart diff.
// NOTE: all unpacks of binned use UNSIGNED >> (dstLocal>=128 sets bit 31;
// signed >> sign-extends to a negative LDS index — r7's crash).
__global__ __launch_bounds__(256) void csr_local(const unsigned* __restrict__ binned,
                                                 const int* __restrict__ bucketStart,
                                                 int* __restrict__ rowStart,
                                                 int* __restrict__ csr, int N, int NB) {
    __shared__ int lcount[256];
    __shared__ int sbuf[256];
    __shared__ int ccur[256];
    __shared__ int buf[BCAP];
    int t = threadIdx.x;
    int b = blockIdx.x;
    int nodeBase = b << 8;
    int nNodes = min(256, N - nodeBase);
    int beg = bucketStart[b], end = bucketStart[b + 1];
    int cnt = end - beg;

    lcount[t] = 0;
    __syncthreads();
    for (int i = t; i < cnt; i += 256) atomicAdd(&lcount[binned[beg + i] >> 24], 1);
    __syncthreads();
    // exclusive scan of lcount
    int v = lcount[t];
    sbuf[t] = v;
    __syncthreads();
    for (int d = 1; d < 256; d <<= 1) {
        int add = (t >= d) ? sbuf[t - d] : 0;
        __syncthreads();
        sbuf[t] += add;
        __syncthreads();
    }
    int excl = sbuf[t] - v;
    ccur[t] = excl;
    if (t < nNodes) rowStart[nodeBase + t] = beg + excl;
    if (b == NB - 1 && t == 0) rowStart[N] = end;
    __syncthreads();

    if (cnt <= BCAP) {
        for (int i = t; i < cnt; i += 256) {
            unsigned u = binned[beg + i];
            int pos = atomicAdd(&ccur[u >> 24], 1);
            buf[pos] = (int)(u & 0x00FFFFFFu);
        }
        __syncthreads();
        for (int i = t; i < cnt; i += 256) csr[beg + i] = buf[i];  // coalesced
    } else {
        // huge-bucket fallback (correct, uncoalesced; never hit for random graphs)
        for (int i = t; i < cnt; i += 256) {
            unsigned u = binned[beg + i];
            int pos = atomicAdd(&ccur[u >> 24], 1);
            csr[beg + pos] = (int)(u & 0x00FFFFFFu);
        }
    }
}

// ================= aggregate (bf16 in / bf16 out, fp32 accumulate) =================
__global__ __launch_bounds__(256) void aggregate_bf16(
    const unsigned short* __restrict__ h, const int* __restrict__ rowStart,
    const int* __restrict__ csr, unsigned short* __restrict__ agg, int N) {
    int wid  = (blockIdx.x * blockDim.x + threadIdx.x) >> 6;
    int lane = threadIdx.x & 63;
    int nw   = (gridDim.x * blockDim.x) >> 6;
    int g = lane >> 4;   // edge subset
    int q = lane & 15;   // 8B chunk
    for (int node = wid; node < N; node += nw) {
        int beg = rowStart[node], end = rowStart[node + 1];
        float a0 = 0.f, a1 = 0.f, a2 = 0.f, a3 = 0.f;
        for (int p = beg + g; p < end; p += 4) {
            int s = csr[p];
            uint2 v = *(const uint2*)(h + (size_t)s * D + q * 4);
            a0 += bf2f_lo(v.x); a1 += bf2f_hi(v.x);
            a2 += bf2f_lo(v.y); a3 += bf2f_hi(v.y);
        }
        a0 += __shfl_xor(a0, 16); a1 += __shfl_xor(a1, 16);
        a2 += __shfl_xor(a2, 16); a3 += __shfl_xor(a3, 16);
        a0 += __shfl_xor(a0, 32); a1 += __shfl_xor(a1, 32);
        a2 += __shfl_xor(a2, 32); a3 += __shfl_xor(a3, 32);
        if (g == 0) {
            float inv = 1.0f / fmaxf((float)(end - beg), 1.0f);
            uint2 o;
            o.x = (unsigned)f2bf(a0 * inv) | ((unsigned)f2bf(a1 * inv) << 16);
            o.y = (unsigned)f2bf(a2 * inv) | ((unsigned)f2bf(a3 * inv) << 16);
            *(uint2*)(agg + (size_t)node * D + q * 4) = o;
        }
    }
}

// ================= transform via MFMA (+ optional fused classifier) =================
// out[N,64] = relu?( [agg|h][N,128] @ Wcat[128,64] + bl );  CLS: out2[N,2] = h3 @ Wout^T + bout
// A = weight frags, B = data rows. Wave: 16 rows x 64 cols = 16 MFMA.
// D frag: row index = lane&15, feature = ot*16 + (lane>>4)*4 + j   (verified r6)
template <bool RELU, bool CLS>
__global__ __launch_bounds__(256) void transform_mfma(
    const unsigned short* __restrict__ agg, const unsigned short* __restrict__ h,
    const unsigned short* __restrict__ wbuf, const float* __restrict__ bl,
    const float* __restrict__ Wout, const float* __restrict__ bout,
    unsigned short* __restrict__ out, float* __restrict__ out2, int N) {
    int t = threadIdx.x;
    int lane = t & 63;
    int w = t >> 6;
    int rq = lane & 15;
    int kg = lane >> 4;

    bf16x8 wf[16];
#pragma unroll
    for (int f = 0; f < 16; ++f)
        wf[f] = *(const bf16x8*)(wbuf + ((size_t)f * 64 + lane) * 8);
    float4 bias[4];
#pragma unroll
    for (int ot = 0; ot < 4; ++ot)
        bias[ot] = *(const float4*)(bl + ot * 16 + kg * 4);
    float4 wo0[4], wo1[4];
    float b0 = 0.f, b1 = 0.f;
    if (CLS) {
#pragma unroll
        for (int ot = 0; ot < 4; ++ot) {
            wo0[ot] = *(const float4*)(Wout + ot * 16 + kg * 4);
            wo1[ot] = *(const float4*)(Wout + D + ot * 16 + kg * 4);
        }
        b0 = bout[0]; b1 = bout[1];
    }

    int tiles = (N + 15) >> 4;
    for (int tile = blockIdx.x * 4 + w; tile < tiles; tile += gridDim.x * 4) {
        int r = tile * 16 + rq;
        int rc = min(r, N - 1);
        const unsigned short* ar = agg + (size_t)rc * D;
        const unsigned short* hr = h + (size_t)rc * D;
        bf16x8 d0 = *(const bf16x8*)(ar + kg * 8);
        bf16x8 d1 = *(const bf16x8*)(ar + 32 + kg * 8);
        bf16x8 d2 = *(const bf16x8*)(hr + kg * 8);
        bf16x8 d3 = *(const bf16x8*)(hr + 32 + kg * 8);

        f32x4 acc0 = {0.f, 0.f, 0.f, 0.f}, acc1 = acc0, acc2 = acc0, acc3 = acc0;
        acc0 = __builtin_amdgcn_mfma_f32_16x16x32_bf16(wf[0],  d0, acc0, 0, 0, 0);
        acc0 = __builtin_amdgcn_mfma_f32_16x16x32_bf16(wf[1],  d1, acc0, 0, 0, 0);
        acc0 = __builtin_amdgcn_mfma_f32_16x16x32_bf16(wf[2],  d2, acc0, 0, 0, 0);
        acc0 = __builtin_amdgcn_mfma_f32_16x16x32_bf16(wf[3],  d3, acc0, 0, 0, 0);
        acc1 = __builtin_amdgcn_mfma_f32_16x16x32_bf16(wf[4],  d0, acc1, 0, 0, 0);
        acc1 = __builtin_amdgcn_mfma_f32_16x16x32_bf16(wf[5],  d1, acc1, 0, 0, 0);
        acc1 = __builtin_amdgcn_mfma_f32_16x16x32_bf16(wf[6],  d2, acc1, 0, 0, 0);
        acc1 = __builtin_amdgcn_mfma_f32_16x16x32_bf16(wf[7],  d3, acc1, 0, 0, 0);
        acc2 = __builtin_amdgcn_mfma_f32_16x16x32_bf16(wf[8],  d0, acc2, 0, 0, 0);
        acc2 = __builtin_amdgcn_mfma_f32_16x16x32_bf16(wf[9],  d1, acc2, 0, 0, 0);
        acc2 = __builtin_amdgcn_mfma_f32_16x16x32_bf16(wf[10], d2, acc2, 0, 0, 0);
        acc2 = __builtin_amdgcn_mfma_f32_16x16x32_bf16(wf[11], d3, acc2, 0, 0, 0);
        acc3 = __builtin_amdgcn_mfma_f32_16x16x32_bf16(wf[12], d0, acc3, 0, 0, 0);
        acc3 = __builtin_amdgcn_mfma_f32_16x16x32_bf16(wf[13], d1, acc3, 0, 0, 0);
        acc3 = __builtin_amdgcn_mfma_f32_16x16x32_bf16(wf[14], d2, acc3, 0, 0, 0);
        acc3 = __builtin_amdgcn_mfma_f32_16x16x32_bf16(wf[15], d3, acc3, 0, 0, 0);

        f32x4 av[4] = {acc0, acc1, acc2, acc3};
        if (CLS) {
            float p0 = 0.f, p1 = 0.f;
#pragma unroll
            for (int ot = 0; ot < 4; ++ot) {
                float x0 = av[ot][0] + bias[ot].x;
                float x1 = av[ot][1] + bias[ot].y;
                float x2 = av[ot][2] + bias[ot].z;
                float x3 = av[ot][3] + bias[ot].w;
                p0 += x0 * wo0[ot].x + x1 * wo0[ot].y + x2 * wo0[ot].z + x3 * wo0[ot].w;
                p1 += x0 * wo1[ot].x + x1 * wo1[ot].y + x2 * wo1[ot].z + x3 * wo1[ot].w;
            }
            p0 += __shfl_xor(p0, 16); p1 += __shfl_xor(p1, 16);
            p0 += __shfl_xor(p0, 32); p1 += __shfl_xor(p1, 32);
            if (kg == 0 && r < N) {
                out2[(size_t)r * 2 + 0] = p0 + b0;
                out2[(size_t)r * 2 + 1] = p1 + b1;
            }
        } else if (r < N) {
            unsigned short* orow = out + (size_t)r * D + kg * 4;
#pragma unroll
            for (int ot = 0; ot < 4; ++ot) {
                float x0 = av[ot][0] + bias[ot].x;
                float x1 = av[ot][1] + bias[ot].y;
                float x2 = av[ot][2] + bias[ot].z;
                float x3 = av[ot][3] + bias[ot].w;
                if (RELU) {
                    x0 = fmaxf(x0, 0.f); x1 = fmaxf(x1, 0.f);
                    x2 = fmaxf(x2, 0.f); x3 = fmaxf(x3, 0.f);
                }
                uint2 o;
                o.x = (unsigned)f2bf(x0) | ((unsigned)f2bf(x1) << 16);
                o.y = (unsigned)f2bf(x2) | ((unsigned)f2bf(x3) << 16);
                *(uint2*)(orow + ot * 16) = o;
            }
        }
    }
}

extern "C" void kernel_launch(void* const* d_in, const int* in_sizes, int n_in,
                              void* d_out, int out_size, void* d_ws, size_t ws_size,
                              hipStream_t stream) {
    const float* x    = (const float*)d_in[0];
    const int*   ei   = (const int*)d_in[1];
    const float* Wl   = (const float*)d_in[2];
    const float* bl   = (const float*)d_in[3];
    const float* Wr   = (const float*)d_in[4];
    const float* Wout = (const float*)d_in[5];
    const float* bout = (const float*)d_in[6];
    float*       out  = (float*)d_out;

    const int N = in_sizes[0] / D;
    const int E = in_sizes[1] / 2;
    const int* src = ei;
    const int* dst = ei + E;
    const int NB = (N + 255) >> 8;  // <= NBMAX for N <= 131072

    char* ws = (char*)d_ws;
    size_t off = 0;
    auto alloc = [&](size_t bytes) {
        char* p = ws + off;
        off = (off + bytes + 255) & ~(size_t)255;
        return p;
    };
    int*            bucketCount  = (int*)alloc((size_t)NB * 4);
    int*            bucketStart  = (int*)alloc((size_t)(NB + 1) * 4);
    int*            bucketCursor = (int*)alloc((size_t)NB * 4);
    int*            rowStart     = (int*)alloc((size_t)(N + 1) * 4);
    int*            csr          = (int*)alloc((size_t)E * 4);
    unsigned short* xb           = (unsigned short*)alloc((size_t)N * D * 2);
    unsigned short* hA           = (unsigned short*)alloc((size_t)N * D * 2);
    unsigned short* hB           = (unsigned short*)alloc((size_t)N * D * 2);
    unsigned short* aggB         = (unsigned short*)alloc((size_t)N * D * 2);
    unsigned short* wbuf         = (unsigned short*)alloc((size_t)3 * 16 * 64 * 8 * 2);
    // binned is dead after csr_local; hB is first written in layer 2 -> alias (saves 4MB ws)
    unsigned*       binned       = (unsigned*)hB;

    hipMemsetAsync(bucketCount, 0, (size_t)NB * 4, stream);

    // ---- prep (independent) ----
    f2b_kernel<<<2048, 256, 0, stream>>>(x, xb, N * D / 4);
    wprep_kernel<<<48, 64, 0, stream>>>(Wl, Wr, wbuf);

    // ---- two-level CSR build ----
    bin_count<<<512, 256, 0, stream>>>(dst, bucketCount, E, NB);
    bucket_scan<<<1, 512, 0, stream>>>(bucketCount, bucketStart, bucketCursor, NB);
    bin_scatter<<<512, 256, 0, stream>>>(src, dst, bucketCursor, binned, E, NB);
    csr_local<<<NB, 256, 0, stream>>>(binned, bucketStart, rowStart, csr, N, NB);

    const int WFRAG = 16 * 64 * 8;  // per-layer wbuf stride (ushorts)

    // ---- 3 layers ----
    aggregate_bf16<<<2048, 256, 0, stream>>>(xb, rowStart, csr, aggB, N);
    transform_mfma<true, false><<<1024, 256, 0, stream>>>(
        aggB, xb, wbuf, bl, nullptr, nullptr, hA, nullptr, N);

    aggregate_bf16<<<2048, 256, 0, stream>>>(hA, rowStart, csr, aggB, N);
    transform_mfma<true, false><<<1024, 256, 0, stream>>>(
        aggB, hA, wbuf + WFRAG, bl + D, nullptr, nullptr, hB, nullptr, N);

    aggregate_bf16<<<2048, 256, 0, stream>>>(hB, rowStart, csr, aggB, N);
    transform_mfma<false, true><<<1024, 256, 0, stream>>>(
        aggB, hB, wbuf + 2 * WFRAG, bl + 2 * D, Wout, bout, nullptr, out, N);
}

// Round 10
// 194.924 us; speedup vs baseline: 3.9474x; 1.0512x over previous
//
#include <hip/hip_runtime.h>

#define D 64
#define NBMAX 512   // max buckets (N <= 131072)
#define BCAP 5120   // LDS csr staging capacity per bucket (mean 2560, 30+ sigma margin)

typedef __attribute__((ext_vector_type(8))) short bf16x8;
typedef __attribute__((ext_vector_type(4))) float f32x4;

__device__ __forceinline__ unsigned short f2bf(float x) {
    union { float f; unsigned u; } v; v.f = x;
    unsigned r = v.u + 0x7fff + ((v.u >> 16) & 1);  // RNE
    return (unsigned short)(r >> 16);
}
__device__ __forceinline__ float bf2f_lo(unsigned u) { return __uint_as_float(u << 16); }
__device__ __forceinline__ float bf2f_hi(unsigned u) { return __uint_as_float(u & 0xffff0000u); }

// ================= fp32 -> bf16 convert (x once) + zero bucketCount =================
__global__ void f2b_kernel(const float* __restrict__ in, unsigned short* __restrict__ out, int n4,
                           int* __restrict__ bucketCount, int NB) {
    int i = blockIdx.x * blockDim.x + threadIdx.x;
    if (i < NB) bucketCount[i] = 0;
    int stride = gridDim.x * blockDim.x;
    for (int j = i; j < n4; j += stride) {
        float4 v = ((const float4*)in)[j];
        ushort4 o;
        o.x = f2bf(v.x); o.y = f2bf(v.y); o.z = f2bf(v.z); o.w = f2bf(v.w);
        ((ushort4*)out)[j] = o;
    }
}

// ================= weight prep: pack Wcat = [Wl^T ; Wr^T] into per-lane MFMA A-fragments =================
__global__ void wprep_kernel(const float* __restrict__ Wl, const float* __restrict__ Wr,
                             unsigned short* __restrict__ wbuf) {
    int layer = blockIdx.x >> 4;
    int f = blockIdx.x & 15;
    int ot = f >> 2, ks = f & 3;
    int l = threadIdx.x;  // 64
    const float* W = (ks < 2 ? Wl : Wr) + (size_t)layer * D * D;
    const float* srcp = W + (size_t)(ot * 16 + (l & 15)) * D + (ks & 1) * 32 + (l >> 4) * 8;
    float4 w0 = *(const float4*)srcp;
    float4 w1 = *(const float4*)(srcp + 4);
    unsigned short* dstp = wbuf + (((size_t)layer * 16 + f) * 64 + l) * 8;
    dstp[0] = f2bf(w0.x); dstp[1] = f2bf(w0.y); dstp[2] = f2bf(w0.z); dstp[3] = f2bf(w0.w);
    dstp[4] = f2bf(w1.x); dstp[5] = f2bf(w1.y); dstp[6] = f2bf(w1.z); dstp[7] = f2bf(w1.w);
}

// ================= two-level CSR build =================
// bucket = dst >> 8 (256 nodes per bucket)

__global__ __launch_bounds__(256) void bin_count(const int* __restrict__ dst,
                                                 int* __restrict__ bucketCount, int E, int NB) {
    __shared__ int hst[NBMAX];
    int t = threadIdx.x;
    for (int i = t; i < NBMAX; i += 256) hst[i] = 0;
    __syncthreads();
    int per = (E + gridDim.x - 1) / gridDim.x;
    int beg = blockIdx.x * per;
    int end = min(E, beg + per);
    for (int e = beg + t; e < end; e += 256) atomicAdd(&hst[dst[e] >> 8], 1);
    __syncthreads();
    for (int i = t; i < NB; i += 256)
        if (hst[i]) atomicAdd(&bucketCount[i], hst[i]);
}

// 1 block, 512 threads: exclusive scan -> bucketStart[NB+1], init bucketCursor
__global__ void bucket_scan(const int* __restrict__ bucketCount, int* __restrict__ bucketStart,
                            int* __restrict__ bucketCursor, int NB) {
    __shared__ int s[512];
    int t = threadIdx.x;
    int v = (t < NB) ? bucketCount[t] : 0;
    s[t] = v;
    __syncthreads();
    for (int d = 1; d < 512; d <<= 1) {
        int add = (t >= d) ? s[t - d] : 0;
        __syncthreads();
        s[t] += add;
        __syncthreads();
    }
    if (t < NB) {
        bucketStart[t] = s[t] - v;
        bucketCursor[t] = s[t] - v;
        if (t == NB - 1) bucketStart[NB] = s[t];
    }
}

// bin edges into buckets; per-(block,bucket) ranges reserved via ONE atomic.
// binned entry (UNSIGNED): (dstLocal << 24) | src   (src < 2^24)
__global__ __launch_bounds__(256) void bin_scatter(const int* __restrict__ src,
                                                   const int* __restrict__ dst,
                                                   int* __restrict__ bucketCursor,
                                                   unsigned* __restrict__ binned, int E, int NB) {
    __shared__ int hst[NBMAX];
    int t = threadIdx.x;
    for (int i = t; i < NBMAX; i += 256) hst[i] = 0;
    __syncthreads();
    int per = (E + gridDim.x - 1) / gridDim.x;
    int beg = blockIdx.x * per;
    int end = min(E, beg + per);
    int ed[8];
#pragma unroll 8
    for (int k = 0; k < 8; ++k) {
        int e = beg + t + k * 256;
        if (e < end) {
            int d = dst[e];
            ed[k] = d;
            atomicAdd(&hst[d >> 8], 1);
        } else ed[k] = -1;
    }
    __syncthreads();
    for (int i = t; i < NB; i += 256) {
        int c = hst[i];
        if (c) hst[i] = atomicAdd(&bucketCursor[i], c);
    }
    __syncthreads();
#pragma unroll 8
    for (int k = 0; k < 8; ++k) {
        int e = beg + t + k * 256;
        if (e < end) {
            int d = ed[k];
            int pos = atomicAdd(&hst[d >> 8], 1);
            binned[pos] = (unsigned)src[e] | ((unsigned)(d & 255) << 24);
        }
    }
}

// one block per bucket: build exact per-node CSR in LDS, flush coalesced.
// all unpacks UNSIGNED >> (r7 lesson: signed >> sign-extends dstLocal>=128).
__global__ __launch_bounds__(256) void csr_local(const unsigned* __restrict__ binned,
                                                 const int* __restrict__ bucketStart,
                                                 int* __restrict__ rowStart,
                                                 int* __restrict__ csr, int N, int NB) {
    __shared__ int lcount[256];
    __shared__ int sbuf[256];
    __shared__ int ccur[256];
    __shared__ int buf[BCAP];
    int t = threadIdx.x;
    int b = blockIdx.x;
    int nodeBase = b << 8;
    int nNodes = min(256, N - nodeBase);
    int beg = bucketStart[b], end = bucketStart[b + 1];
    int cnt = end - beg;

    lcount[t] = 0;
    __syncthreads();
    for (int i = t; i < cnt; i += 256) atomicAdd(&lcount[binned[beg + i] >> 24], 1);
    __syncthreads();
    int v = lcount[t];
    sbuf[t] = v;
    __syncthreads();
    for (int d = 1; d < 256; d <<= 1) {
        int add = (t >= d) ? sbuf[t - d] : 0;
        __syncthreads();
        sbuf[t] += add;
        __syncthreads();
    }
    int excl = sbuf[t] - v;
    ccur[t] = excl;
    if (t < nNodes) rowStart[nodeBase + t] = beg + excl;
    if (b == NB - 1 && t == 0) rowStart[N] = end;
    __syncthreads();

    if (cnt <= BCAP) {
        for (int i = t; i < cnt; i += 256) {
            unsigned u = binned[beg + i];
            int pos = atomicAdd(&ccur[u >> 24], 1);
            buf[pos] = (int)(u & 0x00FFFFFFu);
        }
        __syncthreads();
        for (int i = t; i < cnt; i += 256) csr[beg + i] = buf[i];  // coalesced
    } else {
        for (int i = t; i < cnt; i += 256) {
            unsigned u = binned[beg + i];
            int pos = atomicAdd(&ccur[u >> 24], 1);
            csr[beg + pos] = (int)(u & 0x00FFFFFFu);
        }
    }
}

// ================= aggregate (bf16 in / bf16 out, fp32 accumulate) =================
// 8 groups of 8 lanes; group g handles edges k = g, g+8, ... -> 8 gathers in flight.
// CSR indices preloaded (ci, converged) and distributed via __shfl.
// r9 LESSON: __shfl source lanes MUST be active — a divergent loop made group m
// exit while its lanes were still shfl-sources (deg=9 -> lane 8 dead -> read 0).
// Fix: wave-uniform iteration count; predicate only the ACCUMULATE, never the shfl.
__global__ __launch_bounds__(256) void aggregate_bf16(
    const unsigned short* __restrict__ h, const int* __restrict__ rowStart,
    const int* __restrict__ csr, unsigned short* __restrict__ agg, int N) {
    int wid  = (blockIdx.x * blockDim.x + threadIdx.x) >> 6;
    int lane = threadIdx.x & 63;
    int nw   = (gridDim.x * blockDim.x) >> 6;
    int g = lane >> 3;   // 0..7: edge subset
    int o = lane & 7;    // 16B chunk within the 128B row
    for (int node = wid; node < N; node += nw) {
        int beg = rowStart[node], end = rowStart[node + 1];
        int deg = end - beg;
        int ci = (beg + lane < end) ? csr[beg + lane] : 0;  // converged load; 0 for pad lanes
        float a0 = 0.f, a1 = 0.f, a2 = 0.f, a3 = 0.f, a4 = 0.f, a5 = 0.f, a6 = 0.f, a7 = 0.f;
        int kmax = min(deg, 64);
        int iters = (kmax + 7) >> 3;         // wave-uniform -> wave stays converged
        for (int m = 0; m < iters; ++m) {
            int k = g + (m << 3);
            int s = __shfl(ci, k);           // all 64 lanes active; k>=kmax reads a defined 0
            uint4 v = *(const uint4*)(h + (size_t)s * D + o * 8);
            if (k < kmax) {                  // predicate accumulate only
                a0 += bf2f_lo(v.x); a1 += bf2f_hi(v.x);
                a2 += bf2f_lo(v.y); a3 += bf2f_hi(v.y);
                a4 += bf2f_lo(v.z); a5 += bf2f_hi(v.z);
                a6 += bf2f_lo(v.w); a7 += bf2f_hi(v.w);
            }
        }
        for (int k = 64 + g; k < deg; k += 8) {  // deg>64 fallback: direct loads, no shfl
            int s = csr[beg + k];
            uint4 v = *(const uint4*)(h + (size_t)s * D + o * 8);
            a0 += bf2f_lo(v.x); a1 += bf2f_hi(v.x);
            a2 += bf2f_lo(v.y); a3 += bf2f_hi(v.y);
            a4 += bf2f_lo(v.z); a5 += bf2f_hi(v.z);
            a6 += bf2f_lo(v.w); a7 += bf2f_hi(v.w);
        }
#pragma unroll
        for (int off = 8; off < 64; off <<= 1) {
            a0 += __shfl_xor(a0, off); a1 += __shfl_xor(a1, off);
            a2 += __shfl_xor(a2, off); a3 += __shfl_xor(a3, off);
            a4 += __shfl_xor(a4, off); a5 += __shfl_xor(a5, off);
            a6 += __shfl_xor(a6, off); a7 += __shfl_xor(a7, off);
        }
        if (g == 0) {
            float inv = 1.0f / fmaxf((float)deg, 1.0f);
            uint4 ov;
            ov.x = (unsigned)f2bf(a0 * inv) | ((unsigned)f2bf(a1 * inv) << 16);
            ov.y = (unsigned)f2bf(a2 * inv) | ((unsigned)f2bf(a3 * inv) << 16);
            ov.z = (unsigned)f2bf(a4 * inv) | ((unsigned)f2bf(a5 * inv) << 16);
            ov.w = (unsigned)f2bf(a6 * inv) | ((unsigned)f2bf(a7 * inv) << 16);
            *(uint4*)(agg + (size_t)node * D + o * 8) = ov;
        }
    }
}

// ================= transform via MFMA (+ optional fused classifier) =================
// out[N,64] = relu?( [agg|h][N,128] @ Wcat[128,64] + bl );  CLS: out2[N,2] = h3 @ Wout^T + bout
// D frag: row index = lane&15, feature = ot*16 + (lane>>4)*4 + j   (verified r6)
template <bool RELU, bool CLS>
__global__ __launch_bounds__(256) void transform_mfma(
    const unsigned short* __restrict__ agg, const unsigned short* __restrict__ h,
    const unsigned short* __restrict__ wbuf, const float* __restrict__ bl,
    const float* __restrict__ Wout, const float* __restrict__ bout,
    unsigned short* __restrict__ out, float* __restrict__ out2, int N) {
    int t = threadIdx.x;
    int lane = t & 63;
    int w = t >> 6;
    int rq = lane & 15;
    int kg = lane >> 4;

    bf16x8 wf[16];
#pragma unroll
    for (int f = 0; f < 16; ++f)
        wf[f] = *(const bf16x8*)(wbuf + ((size_t)f * 64 + lane) * 8);
    float4 bias[4];
#pragma unroll
    for (int ot = 0; ot < 4; ++ot)
        bias[ot] = *(const float4*)(bl + ot * 16 + kg * 4);
    float4 wo0[4], wo1[4];
    float b0 = 0.f, b1 = 0.f;
    if (CLS) {
#pragma unroll
        for (int ot = 0; ot < 4; ++ot) {
            wo0[ot] = *(const float4*)(Wout + ot * 16 + kg * 4);
            wo1[ot] = *(const float4*)(Wout + D + ot * 16 + kg * 4);
        }
        b0 = bout[0]; b1 = bout[1];
    }

    int tiles = (N + 15) >> 4;
    for (int tile = blockIdx.x * 4 + w; tile < tiles; tile += gridDim.x * 4) {
        int r = tile * 16 + rq;
        int rc = min(r, N - 1);
        const unsigned short* ar = agg + (size_t)rc * D;
        const unsigned short* hr = h + (size_t)rc * D;
        bf16x8 d0 = *(const bf16x8*)(ar + kg * 8);
        bf16x8 d1 = *(const bf16x8*)(ar + 32 + kg * 8);
        bf16x8 d2 = *(const bf16x8*)(hr + kg * 8);
        bf16x8 d3 = *(const bf16x8*)(hr + 32 + kg * 8);

        f32x4 acc0 = {0.f, 0.f, 0.f, 0.f}, acc1 = acc0, acc2 = acc0, acc3 = acc0;
        acc0 = __builtin_amdgcn_mfma_f32_16x16x32_bf16(wf[0],  d0, acc0, 0, 0, 0);
        acc0 = __builtin_amdgcn_mfma_f32_16x16x32_bf16(wf[1],  d1, acc0, 0, 0, 0);
        acc0 = __builtin_amdgcn_mfma_f32_16x16x32_bf16(wf[2],  d2, acc0, 0, 0, 0);
        acc0 = __builtin_amdgcn_mfma_f32_16x16x32_bf16(wf[3],  d3, acc0, 0, 0, 0);
        acc1 = __builtin_amdgcn_mfma_f32_16x16x32_bf16(wf[4],  d0, acc1, 0, 0, 0);
        acc1 = __builtin_amdgcn_mfma_f32_16x16x32_bf16(wf[5],  d1, acc1, 0, 0, 0);
        acc1 = __builtin_amdgcn_mfma_f32_16x16x32_bf16(wf[6],  d2, acc1, 0, 0, 0);
        acc1 = __builtin_amdgcn_mfma_f32_16x16x32_bf16(wf[7],  d3, acc1, 0, 0, 0);
        acc2 = __builtin_amdgcn_mfma_f32_16x16x32_bf16(wf[8],  d0, acc2, 0, 0, 0);
        acc2 = __builtin_amdgcn_mfma_f32_16x16x32_bf16(wf[9],  d1, acc2, 0, 0, 0);
        acc2 = __builtin_amdgcn_mfma_f32_16x16x32_bf16(wf[10], d2, acc2, 0, 0, 0);
        acc2 = __builtin_amdgcn_mfma_f32_16x16x32_bf16(wf[11], d3, acc2, 0, 0, 0);
        acc3 = __builtin_amdgcn_mfma_f32_16x16x32_bf16(wf[12], d0, acc3, 0, 0, 0);
        acc3 = __builtin_amdgcn_mfma_f32_16x16x32_bf16(wf[13], d1, acc3, 0, 0, 0);
        acc3 = __builtin_amdgcn_mfma_f32_16x16x32_bf16(wf[14], d2, acc3, 0, 0, 0);
        acc3 = __builtin_amdgcn_mfma_f32_16x16x32_bf16(wf[15], d3, acc3, 0, 0, 0);

        f32x4 av[4] = {acc0, acc1, acc2, acc3};
        if (CLS) {
            float p0 = 0.f, p1 = 0.f;
#pragma unroll
            for (int ot = 0; ot < 4; ++ot) {
                float x0 = av[ot][0] + bias[ot].x;
                float x1 = av[ot][1] + bias[ot].y;
                float x2 = av[ot][2] + bias[ot].z;
                float x3 = av[ot][3] + bias[ot].w;
                p0 += x0 * wo0[ot].x + x1 * wo0[ot].y + x2 * wo0[ot].z + x3 * wo0[ot].w;
                p1 += x0 * wo1[ot].x + x1 * wo1[ot].y + x2 * wo1[ot].z + x3 * wo1[ot].w;
            }
            p0 += __shfl_xor(p0, 16); p1 += __shfl_xor(p1, 16);
            p0 += __shfl_xor(p0, 32); p1 += __shfl_xor(p1, 32);
            if (kg == 0 && r < N) {
                out2[(size_t)r * 2 + 0] = p0 + b0;
                out2[(size_t)r * 2 + 1] = p1 + b1;
            }
        } else if (r < N) {
            unsigned short* orow = out + (size_t)r * D + kg * 4;
#pragma unroll
            for (int ot = 0; ot < 4; ++ot) {
                float x0 = av[ot][0] + bias[ot].x;
                float x1 = av[ot][1] + bias[ot].y;
                float x2 = av[ot][2] + bias[ot].z;
                float x3 = av[ot][3] + bias[ot].w;
                if (RELU) {
                    x0 = fmaxf(x0, 0.f); x1 = fmaxf(x1, 0.f);
                    x2 = fmaxf(x2, 0.f); x3 = fmaxf(x3, 0.f);
                }
                uint2 o;
                o.x = (unsigned)f2bf(x0) | ((unsigned)f2bf(x1) << 16);
                o.y = (unsigned)f2bf(x2) | ((unsigned)f2bf(x3) << 16);
                *(uint2*)(orow + ot * 16) = o;
            }
        }
    }
}

extern "C" void kernel_launch(void* const* d_in, const int* in_sizes, int n_in,
                              void* d_out, int out_size, void* d_ws, size_t ws_size,
                              hipStream_t stream) {
    const float* x    = (const float*)d_in[0];
    const int*   ei   = (const int*)d_in[1];
    const float* Wl   = (const float*)d_in[2];
    const float* bl   = (const float*)d_in[3];
    const float* Wr   = (const float*)d_in[4];
    const float* Wout = (const float*)d_in[5];
    const float* bout = (const float*)d_in[6];
    float*       out  = (float*)d_out;

    const int N = in_sizes[0] / D;
    const int E = in_sizes[1] / 2;
    const int* src = ei;
    const int* dst = ei + E;
    const int NB = (N + 255) >> 8;  // <= NBMAX for N <= 131072

    char* ws = (char*)d_ws;
    size_t off = 0;
    auto alloc = [&](size_t bytes) {
        char* p = ws + off;
        off = (off + bytes + 255) & ~(size_t)255;
        return p;
    };
    int*            bucketCount  = (int*)alloc((size_t)NB * 4);
    int*            bucketStart  = (int*)alloc((size_t)(NB + 1) * 4);
    int*            bucketCursor = (int*)alloc((size_t)NB * 4);
    int*            rowStart     = (int*)alloc((size_t)(N + 1) * 4);
    int*            csr          = (int*)alloc((size_t)E * 4);
    unsigned short* xb           = (unsigned short*)alloc((size_t)N * D * 2);
    unsigned short* hA           = (unsigned short*)alloc((size_t)N * D * 2);
    unsigned short* hB           = (unsigned short*)alloc((size_t)N * D * 2);
    unsigned short* aggB         = (unsigned short*)alloc((size_t)N * D * 2);
    unsigned short* wbuf         = (unsigned short*)alloc((size_t)3 * 16 * 64 * 8 * 2);
    // binned is dead after csr_local; hB is first written in layer 2 -> alias (saves 4MB ws)
    unsigned*       binned       = (unsigned*)hB;

    // ---- prep (f2b also zeroes bucketCount -> no hipMemsetAsync anywhere) ----
    f2b_kernel<<<2048, 256, 0, stream>>>(x, xb, N * D / 4, bucketCount, NB);
    wprep_kernel<<<48, 64, 0, stream>>>(Wl, Wr, wbuf);

    // ---- two-level CSR build ----
    bin_count<<<512, 256, 0, stream>>>(dst, bucketCount, E, NB);
    bucket_scan<<<1, 512, 0, stream>>>(bucketCount, bucketStart, bucketCursor, NB);
    bin_scatter<<<512, 256, 0, stream>>>(src, dst, bucketCursor, binned, E, NB);
    csr_local<<<NB, 256, 0, stream>>>(binned, bucketStart, rowStart, csr, N, NB);

    const int WFRAG = 16 * 64 * 8;  // per-layer wbuf stride (ushorts)

    // ---- 3 layers ----
    aggregate_bf16<<<2048, 256, 0, stream>>>(xb, rowStart, csr, aggB, N);
    transform_mfma<true, false><<<1024, 256, 0, stream>>>(
        aggB, xb, wbuf, bl, nullptr, nullptr, hA, nullptr, N);

    aggregate_bf16<<<2048, 256, 0, stream>>>(hA, rowStart, csr, aggB, N);
    transform_mfma<true, false><<<1024, 256, 0, stream>>>(
        aggB, hA, wbuf + WFRAG, bl + D, nullptr, nullptr, hB, nullptr, N);

    aggregate_bf16<<<2048, 256, 0, stream>>>(hB, rowStart, csr, aggB, N);
    transform_mfma<false, true><<<1024, 256, 0, stream>>>(
        aggB, hB, wbuf + 2 * WFRAG, bl + 2 * D, Wout, bout, nullptr, out, N);
}

// Round 11
// 159.430 us; speedup vs baseline: 4.8263x; 1.2226x over previous
//
#include <hip/hip_runtime.h>

#define D 64
#define NBMAX 512   // max buckets (N <= 131072)
#define BCAP 5120   // LDS csr staging capacity per bucket (mean 2560, 30+ sigma margin)

typedef __attribute__((ext_vector_type(8))) short bf16x8;
typedef __attribute__((ext_vector_type(4))) float f32x4;

__device__ __forceinline__ unsigned short f2bf(float x) {
    union { float f; unsigned u; } v; v.f = x;
    unsigned r = v.u + 0x7fff + ((v.u >> 16) & 1);  // RNE
    return (unsigned short)(r >> 16);
}
__device__ __forceinline__ float bf2f_lo(unsigned u) { return __uint_as_float(u << 16); }
__device__ __forceinline__ float bf2f_hi(unsigned u) { return __uint_as_float(u & 0xffff0000u); }

// ================= fp32 -> bf16 convert (x once) + zero bucketCount =================
__global__ void f2b_kernel(const float* __restrict__ in, unsigned short* __restrict__ out, int n4,
                           int* __restrict__ bucketCount, int NB) {
    int i = blockIdx.x * blockDim.x + threadIdx.x;
    if (i < NB) bucketCount[i] = 0;
    int stride = gridDim.x * blockDim.x;
    for (int j = i; j < n4; j += stride) {
        float4 v = ((const float4*)in)[j];
        ushort4 o;
        o.x = f2bf(v.x); o.y = f2bf(v.y); o.z = f2bf(v.z); o.w = f2bf(v.w);
        ((ushort4*)out)[j] = o;
    }
}

// ================= weight prep: pack Wcat = [Wl^T ; Wr^T] into per-lane MFMA A-fragments =================
__global__ void wprep_kernel(const float* __restrict__ Wl, const float* __restrict__ Wr,
                             unsigned short* __restrict__ wbuf) {
    int layer = blockIdx.x >> 4;
    int f = blockIdx.x & 15;
    int ot = f >> 2, ks = f & 3;
    int l = threadIdx.x;  // 64
    const float* W = (ks < 2 ? Wl : Wr) + (size_t)layer * D * D;
    const float* srcp = W + (size_t)(ot * 16 + (l & 15)) * D + (ks & 1) * 32 + (l >> 4) * 8;
    float4 w0 = *(const float4*)srcp;
    float4 w1 = *(const float4*)(srcp + 4);
    unsigned short* dstp = wbuf + (((size_t)layer * 16 + f) * 64 + l) * 8;
    dstp[0] = f2bf(w0.x); dstp[1] = f2bf(w0.y); dstp[2] = f2bf(w0.z); dstp[3] = f2bf(w0.w);
    dstp[4] = f2bf(w1.x); dstp[5] = f2bf(w1.y); dstp[6] = f2bf(w1.z); dstp[7] = f2bf(w1.w);
}

// ================= two-level CSR build =================
// bucket = dst >> 8 (256 nodes per bucket)

__global__ __launch_bounds__(256) void bin_count(const int* __restrict__ dst,
                                                 int* __restrict__ bucketCount, int E, int NB) {
    __shared__ int hst[NBMAX];
    int t = threadIdx.x;
    for (int i = t; i < NBMAX; i += 256) hst[i] = 0;
    __syncthreads();
    int per = (E + gridDim.x - 1) / gridDim.x;
    int beg = blockIdx.x * per;
    int end = min(E, beg + per);
    for (int e = beg + t; e < end; e += 256) atomicAdd(&hst[dst[e] >> 8], 1);
    __syncthreads();
    for (int i = t; i < NB; i += 256)
        if (hst[i]) atomicAdd(&bucketCount[i], hst[i]);
}

// 1 block, 512 threads: exclusive scan -> bucketStart[NB+1], init bucketCursor
__global__ void bucket_scan(const int* __restrict__ bucketCount, int* __restrict__ bucketStart,
                            int* __restrict__ bucketCursor, int NB) {
    __shared__ int s[512];
    int t = threadIdx.x;
    int v = (t < NB) ? bucketCount[t] : 0;
    s[t] = v;
    __syncthreads();
    for (int d = 1; d < 512; d <<= 1) {
        int add = (t >= d) ? s[t - d] : 0;
        __syncthreads();
        s[t] += add;
        __syncthreads();
    }
    if (t < NB) {
        bucketStart[t] = s[t] - v;
        bucketCursor[t] = s[t] - v;
        if (t == NB - 1) bucketStart[NB] = s[t];
    }
}

// bin edges into buckets; per-(block,bucket) ranges reserved via ONE atomic.
// binned entry (UNSIGNED): (dstLocal << 24) | src   (src < 2^24)
__global__ __launch_bounds__(256) void bin_scatter(const int* __restrict__ src,
                                                   const int* __restrict__ dst,
                                                   int* __restrict__ bucketCursor,
                                                   unsigned* __restrict__ binned, int E, int NB) {
    __shared__ int hst[NBMAX];
    int t = threadIdx.x;
    for (int i = t; i < NBMAX; i += 256) hst[i] = 0;
    __syncthreads();
    int per = (E + gridDim.x - 1) / gridDim.x;
    int beg = blockIdx.x * per;
    int end = min(E, beg + per);
    int ed[8];
#pragma unroll 8
    for (int k = 0; k < 8; ++k) {
        int e = beg + t + k * 256;
        if (e < end) {
            int d = dst[e];
            ed[k] = d;
            atomicAdd(&hst[d >> 8], 1);
        } else ed[k] = -1;
    }
    __syncthreads();
    for (int i = t; i < NB; i += 256) {
        int c = hst[i];
        if (c) hst[i] = atomicAdd(&bucketCursor[i], c);
    }
    __syncthreads();
#pragma unroll 8
    for (int k = 0; k < 8; ++k) {
        int e = beg + t + k * 256;
        if (e < end) {
            int d = ed[k];
            int pos = atomicAdd(&hst[d >> 8], 1);
            binned[pos] = (unsigned)src[e] | ((unsigned)(d & 255) << 24);
        }
    }
}

// one block per bucket: build exact per-node CSR in LDS, flush coalesced.
// all unpacks UNSIGNED >> (r7 lesson: signed >> sign-extends dstLocal>=128).
__global__ __launch_bounds__(256) void csr_local(const unsigned* __restrict__ binned,
                                                 const int* __restrict__ bucketStart,
                                                 int* __restrict__ rowStart,
                                                 int* __restrict__ csr, int N, int NB) {
    __shared__ int lcount[256];
    __shared__ int sbuf[256];
    __shared__ int ccur[256];
    __shared__ int buf[BCAP];
    int t = threadIdx.x;
    int b = blockIdx.x;
    int nodeBase = b << 8;
    int nNodes = min(256, N - nodeBase);
    int beg = bucketStart[b], end = bucketStart[b + 1];
    int cnt = end - beg;

    lcount[t] = 0;
    __syncthreads();
    for (int i = t; i < cnt; i += 256) atomicAdd(&lcount[binned[beg + i] >> 24], 1);
    __syncthreads();
    int v = lcount[t];
    sbuf[t] = v;
    __syncthreads();
    for (int d = 1; d < 256; d <<= 1) {
        int add = (t >= d) ? sbuf[t - d] : 0;
        __syncthreads();
        sbuf[t] += add;
        __syncthreads();
    }
    int excl = sbuf[t] - v;
    ccur[t] = excl;
    if (t < nNodes) rowStart[nodeBase + t] = beg + excl;
    if (b == NB - 1 && t == 0) rowStart[N] = end;
    __syncthreads();

    if (cnt <= BCAP) {
        for (int i = t; i < cnt; i += 256) {
            unsigned u = binned[beg + i];
            int pos = atomicAdd(&ccur[u >> 24], 1);
            buf[pos] = (int)(u & 0x00FFFFFFu);
        }
        __syncthreads();
        for (int i = t; i < cnt; i += 256) csr[beg + i] = buf[i];  // coalesced
    } else {
        for (int i = t; i < cnt; i += 256) {
            unsigned u = binned[beg + i];
            int pos = atomicAdd(&ccur[u >> 24], 1);
            csr[beg + pos] = (int)(u & 0x00FFFFFFu);
        }
    }
}

// ================= aggregate (bf16 in / bf16 out, fp32 accumulate) =================
// r10 restructure: ONE NODE PER 8-LANE GROUP (8 nodes/wave). Lane o owns chunk o
// (16B) of its group's row exclusively across all edges -> NO cross-lane reduce
// shuffles at all (was 24 bpermutes/node), and the epilogue serves 8 nodes at
// once. Indices: lanes preload 8 per group (ci), broadcast via 1 shfl/edge,
// 8-unrolled batches so 8 gathers/group are in flight; next batch's ci
// prefetched under the current batch. Wave iterates to wave-max degree so all
// shfl sources stay active (r9 lesson); accumulate predicated on m<deg.
__global__ __launch_bounds__(256) void aggregate_bf16(
    const unsigned short* __restrict__ h, const int* __restrict__ rowStart,
    const int* __restrict__ csr, unsigned short* __restrict__ agg, int N) {
    int wid  = (blockIdx.x * blockDim.x + threadIdx.x) >> 6;
    int lane = threadIdx.x & 63;
    int nw   = (gridDim.x * blockDim.x) >> 6;
    int g = lane >> 3;        // group = node within octet
    int o = lane & 7;        // 16B chunk / index-preload slot
    int gbase = lane & 56;   // group base lane
    int nOct = (N + 7) >> 3;
    for (int n8 = wid; n8 < nOct; n8 += nw) {
        int node = (n8 << 3) + g;
        bool valid = node < N;
        int beg = 0, end = 0;
        if (valid) { beg = rowStart[node]; end = rowStart[node + 1]; }
        int deg = end - beg;
        // wave-max degree (uniform across wave; group bits are lane bits 3..5)
        int md = deg;
        md = max(md, __shfl_xor(md, 8));
        md = max(md, __shfl_xor(md, 16));
        md = max(md, __shfl_xor(md, 32));
        float a0 = 0.f, a1 = 0.f, a2 = 0.f, a3 = 0.f, a4 = 0.f, a5 = 0.f, a6 = 0.f, a7 = 0.f;
        int ci = (beg + o < end) ? csr[beg + o] : 0;  // first 8 indices of this group
        for (int mb = 0; mb < md; mb += 8) {
            int ciN = 0;  // prefetch next batch's indices under this batch's gathers
            if (mb + 8 < md) ciN = (beg + mb + 8 + o < end) ? csr[beg + mb + 8 + o] : 0;
#pragma unroll
            for (int mm = 0; mm < 8; ++mm) {
                int m = mb + mm;
                int s = __shfl(ci, gbase | mm);  // all 64 lanes active (md uniform)
                uint4 v = *(const uint4*)(h + (size_t)s * D + o * 8);
                if (m < deg) {                   // predicate accumulate only
                    a0 += bf2f_lo(v.x); a1 += bf2f_hi(v.x);
                    a2 += bf2f_lo(v.y); a3 += bf2f_hi(v.y);
                    a4 += bf2f_lo(v.z); a5 += bf2f_hi(v.z);
                    a6 += bf2f_lo(v.w); a7 += bf2f_hi(v.w);
                }
            }
            ci = ciN;
        }
        if (valid) {  // each lane writes its own 16B chunk; no reduction needed
            float inv = 1.0f / fmaxf((float)deg, 1.0f);
            uint4 ov;
            ov.x = (unsigned)f2bf(a0 * inv) | ((unsigned)f2bf(a1 * inv) << 16);
            ov.y = (unsigned)f2bf(a2 * inv) | ((unsigned)f2bf(a3 * inv) << 16);
            ov.z = (unsigned)f2bf(a4 * inv) | ((unsigned)f2bf(a5 * inv) << 16);
            ov.w = (unsigned)f2bf(a6 * inv) | ((unsigned)f2bf(a7 * inv) << 16);
            *(uint4*)(agg + (size_t)node * D + o * 8) = ov;
        }
    }
}

// ================= transform via MFMA (+ optional fused classifier) =================
// out[N,64] = relu?( [agg|h][N,128] @ Wcat[128,64] + bl );  CLS: out2[N,2] = h3 @ Wout^T + bout
// D frag: row index = lane&15, feature = ot*16 + (lane>>4)*4 + j   (verified r6)
template <bool RELU, bool CLS>
__global__ __launch_bounds__(256) void transform_mfma(
    const unsigned short* __restrict__ agg, const unsigned short* __restrict__ h,
    const unsigned short* __restrict__ wbuf, const float* __restrict__ bl,
    const float* __restrict__ Wout, const float* __restrict__ bout,
    unsigned short* __restrict__ out, float* __restrict__ out2, int N) {
    int t = threadIdx.x;
    int lane = t & 63;
    int w = t >> 6;
    int rq = lane & 15;
    int kg = lane >> 4;

    bf16x8 wf[16];
#pragma unroll
    for (int f = 0; f < 16; ++f)
        wf[f] = *(const bf16x8*)(wbuf + ((size_t)f * 64 + lane) * 8);
    float4 bias[4];
#pragma unroll
    for (int ot = 0; ot < 4; ++ot)
        bias[ot] = *(const float4*)(bl + ot * 16 + kg * 4);
    float4 wo0[4], wo1[4];
    float b0 = 0.f, b1 = 0.f;
    if (CLS) {
#pragma unroll
        for (int ot = 0; ot < 4; ++ot) {
            wo0[ot] = *(const float4*)(Wout + ot * 16 + kg * 4);
            wo1[ot] = *(const float4*)(Wout + D + ot * 16 + kg * 4);
        }
        b0 = bout[0]; b1 = bout[1];
    }

    int tiles = (N + 15) >> 4;
    for (int tile = blockIdx.x * 4 + w; tile < tiles; tile += gridDim.x * 4) {
        int r = tile * 16 + rq;
        int rc = min(r, N - 1);
        const unsigned short* ar = agg + (size_t)rc * D;
        const unsigned short* hr = h + (size_t)rc * D;
        bf16x8 d0 = *(const bf16x8*)(ar + kg * 8);
        bf16x8 d1 = *(const bf16x8*)(ar + 32 + kg * 8);
        bf16x8 d2 = *(const bf16x8*)(hr + kg * 8);
        bf16x8 d3 = *(const bf16x8*)(hr + 32 + kg * 8);

        f32x4 acc0 = {0.f, 0.f, 0.f, 0.f}, acc1 = acc0, acc2 = acc0, acc3 = acc0;
        acc0 = __builtin_amdgcn_mfma_f32_16x16x32_bf16(wf[0],  d0, acc0, 0, 0, 0);
        acc0 = __builtin_amdgcn_mfma_f32_16x16x32_bf16(wf[1],  d1, acc0, 0, 0, 0);
        acc0 = __builtin_amdgcn_mfma_f32_16x16x32_bf16(wf[2],  d2, acc0, 0, 0, 0);
        acc0 = __builtin_amdgcn_mfma_f32_16x16x32_bf16(wf[3],  d3, acc0, 0, 0, 0);
        acc1 = __builtin_amdgcn_mfma_f32_16x16x32_bf16(wf[4],  d0, acc1, 0, 0, 0);
        acc1 = __builtin_amdgcn_mfma_f32_16x16x32_bf16(wf[5],  d1, acc1, 0, 0, 0);
        acc1 = __builtin_amdgcn_mfma_f32_16x16x32_bf16(wf[6],  d2, acc1, 0, 0, 0);
        acc1 = __builtin_amdgcn_mfma_f32_16x16x32_bf16(wf[7],  d3, acc1, 0, 0, 0);
        acc2 = __builtin_amdgcn_mfma_f32_16x16x32_bf16(wf[8],  d0, acc2, 0, 0, 0);
        acc2 = __builtin_amdgcn_mfma_f32_16x16x32_bf16(wf[9],  d1, acc2, 0, 0, 0);
        acc2 = __builtin_amdgcn_mfma_f32_16x16x32_bf16(wf[10], d2, acc2, 0, 0, 0);
        acc2 = __builtin_amdgcn_mfma_f32_16x16x32_bf16(wf[11], d3, acc2, 0, 0, 0);
        acc3 = __builtin_amdgcn_mfma_f32_16x16x32_bf16(wf[12], d0, acc3, 0, 0, 0);
        acc3 = __builtin_amdgcn_mfma_f32_16x16x32_bf16(wf[13], d1, acc3, 0, 0, 0);
        acc3 = __builtin_amdgcn_mfma_f32_16x16x32_bf16(wf[14], d2, acc3, 0, 0, 0);
        acc3 = __builtin_amdgcn_mfma_f32_16x16x32_bf16(wf[15], d3, acc3, 0, 0, 0);

        f32x4 av[4] = {acc0, acc1, acc2, acc3};
        if (CLS) {
            float p0 = 0.f, p1 = 0.f;
#pragma unroll
            for (int ot = 0; ot < 4; ++ot) {
                float x0 = av[ot][0] + bias[ot].x;
                float x1 = av[ot][1] + bias[ot].y;
                float x2 = av[ot][2] + bias[ot].z;
                float x3 = av[ot][3] + bias[ot].w;
                p0 += x0 * wo0[ot].x + x1 * wo0[ot].y + x2 * wo0[ot].z + x3 * wo0[ot].w;
                p1 += x0 * wo1[ot].x + x1 * wo1[ot].y + x2 * wo1[ot].z + x3 * wo1[ot].w;
            }
            p0 += __shfl_xor(p0, 16); p1 += __shfl_xor(p1, 16);
            p0 += __shfl_xor(p0, 32); p1 += __shfl_xor(p1, 32);
            if (kg == 0 && r < N) {
                out2[(size_t)r * 2 + 0] = p0 + b0;
                out2[(size_t)r * 2 + 1] = p1 + b1;
            }
        } else if (r < N) {
            unsigned short* orow = out + (size_t)r * D + kg * 4;
#pragma unroll
            for (int ot = 0; ot < 4; ++ot) {
                float x0 = av[ot][0] + bias[ot].x;
                float x1 = av[ot][1] + bias[ot].y;
                float x2 = av[ot][2] + bias[ot].z;
                float x3 = av[ot][3] + bias[ot].w;
                if (RELU) {
                    x0 = fmaxf(x0, 0.f); x1 = fmaxf(x1, 0.f);
                    x2 = fmaxf(x2, 0.f); x3 = fmaxf(x3, 0.f);
                }
                uint2 o;
                o.x = (unsigned)f2bf(x0) | ((unsigned)f2bf(x1) << 16);
                o.y = (unsigned)f2bf(x2) | ((unsigned)f2bf(x3) << 16);
                *(uint2*)(orow + ot * 16) = o;
            }
        }
    }
}

extern "C" void kernel_launch(void* const* d_in, const int* in_sizes, int n_in,
                              void* d_out, int out_size, void* d_ws, size_t ws_size,
                              hipStream_t stream) {
    const float* x    = (const float*)d_in[0];
    const int*   ei   = (const int*)d_in[1];
    const float* Wl   = (const float*)d_in[2];
    const float* bl   = (const float*)d_in[3];
    const float* Wr   = (const float*)d_in[4];
    const float* Wout = (const float*)d_in[5];
    const float* bout = (const float*)d_in[6];
    float*       out  = (float*)d_out;

    const int N = in_sizes[0] / D;
    const int E = in_sizes[1] / 2;
    const int* src = ei;
    const int* dst = ei + E;
    const int NB = (N + 255) >> 8;  // <= NBMAX for N <= 131072

    char* ws = (char*)d_ws;
    size_t off = 0;
    auto alloc = [&](size_t bytes) {
        char* p = ws + off;
        off = (off + bytes + 255) & ~(size_t)255;
        return p;
    };
    int*            bucketCount  = (int*)alloc((size_t)NB * 4);
    int*            bucketStart  = (int*)alloc((size_t)(NB + 1) * 4);
    int*            bucketCursor = (int*)alloc((size_t)NB * 4);
    int*            rowStart     = (int*)alloc((size_t)(N + 1) * 4);
    int*            csr          = (int*)alloc((size_t)E * 4);
    unsigned short* xb           = (unsigned short*)alloc((size_t)N * D * 2);
    unsigned short* hA           = (unsigned short*)alloc((size_t)N * D * 2);
    unsigned short* hB           = (unsigned short*)alloc((size_t)N * D * 2);
    unsigned short* aggB         = (unsigned short*)alloc((size_t)N * D * 2);
    unsigned short* wbuf         = (unsigned short*)alloc((size_t)3 * 16 * 64 * 8 * 2);
    // binned is dead after csr_local; hB is first written in layer 2 -> alias (saves 4MB ws)
    unsigned*       binned       = (unsigned*)hB;

    // ---- prep (f2b also zeroes bucketCount -> no hipMemsetAsync anywhere) ----
    f2b_kernel<<<2048, 256, 0, stream>>>(x, xb, N * D / 4, bucketCount, NB);
    wprep_kernel<<<48, 64, 0, stream>>>(Wl, Wr, wbuf);

    // ---- two-level CSR build ----
    bin_count<<<512, 256, 0, stream>>>(dst, bucketCount, E, NB);
    bucket_scan<<<1, 512, 0, stream>>>(bucketCount, bucketStart, bucketCursor, NB);
    bin_scatter<<<512, 256, 0, stream>>>(src, dst, bucketCursor, binned, E, NB);
    csr_local<<<NB, 256, 0, stream>>>(binned, bucketStart, rowStart, csr, N, NB);

    const int WFRAG = 16 * 64 * 8;  // per-layer wbuf stride (ushorts)

    // ---- 3 layers ----
    aggregate_bf16<<<2048, 256, 0, stream>>>(xb, rowStart, csr, aggB, N);
    transform_mfma<true, false><<<1024, 256, 0, stream>>>(
        aggB, xb, wbuf, bl, nullptr, nullptr, hA, nullptr, N);

    aggregate_bf16<<<2048, 256, 0, stream>>>(hA, rowStart, csr, aggB, N);
    transform_mfma<true, false><<<1024, 256, 0, stream>>>(
        aggB, hA, wbuf + WFRAG, bl + D, nullptr, nullptr, hB, nullptr, N);

    aggregate_bf16<<<2048, 256, 0, stream>>>(hB, rowStart, csr, aggB, N);
    transform_mfma<false, true><<<1024, 256, 0, stream>>>(
        aggB, hB, wbuf + 2 * WFRAG, bl + 2 * D, Wout, bout, nullptr, out, N);
}